// Round 1
// baseline (6825.938 us; speedup 1.0000x reference)
//
#include <hip/hip_runtime.h>
#include <stdint.h>
#include <math.h>

// ---------------------------------------------------------------------------
// IAF_PointNetFeaturePropagation: full f32 pipeline, correctness-first.
// B=4, N=8192, S=2048, K=20, D1=D2=256, CO=128, CLS=21, H=1638+409=2047
// ---------------------------------------------------------------------------

namespace {

constexpr int BB   = 4;
constexpr int NN   = 8192;
constexpr int SS   = 2048;
constexpr int KNB  = 20;
constexpr int CO   = 128;
constexpr int CLS  = 21;
constexpr int HH   = 2047;
constexpr int OUTER= 1638;
constexpr int INNER= 409;

// ======================= numpy default_rng(0).choice(8192,409,replace=False)
// SeedSequence(0) -> PCG64 -> Floyd's algorithm with Lemire32 bounded draws.
// Final shuffle omitted: attention pool is permutation invariant.
__global__ __launch_bounds__(512) void inner_idx_k(int* __restrict__ out) {
  __shared__ uint64_t hs[512];
  hs[threadIdx.x] = ~0ull;
  __syncthreads();
  if (threadIdx.x != 0) return;

  // ---- SeedSequence(0) pool mixing
  uint32_t pool[4];
  uint32_t hc = 0x43b0d7e5u;                       // INIT_A
  auto hashmix = [&hc](uint32_t v) -> uint32_t {
    v ^= hc; hc *= 0x931e8875u; v *= hc; v ^= v >> 16; return v;  // MULT_A
  };
  auto mixf = [](uint32_t x, uint32_t y) -> uint32_t {
    uint32_t r = x * 0xca01f9ddu; r ^= y * 0x4973f715u; r ^= r >> 16; return r;
  };
  pool[0] = hashmix(0u);   // entropy = [0]
  pool[1] = hashmix(0u);
  pool[2] = hashmix(0u);
  pool[3] = hashmix(0u);
  for (int s = 0; s < 4; ++s)
    for (int d = 0; d < 4; ++d)
      if (s != d) pool[d] = mixf(pool[d], hashmix(pool[s]));

  // ---- generate_state(4, uint64): 8 x uint32, pairs little-endian
  uint32_t st32[8];
  uint32_t hb = 0x8b51f9ddu;                       // INIT_B
  for (int i = 0; i < 8; ++i) {
    uint32_t dv = pool[i & 3];
    dv ^= hb; hb *= 0x58f38dedu; dv *= hb; dv ^= dv >> 16;   // MULT_B
    st32[i] = dv;
  }
  uint64_t s64[4];
  for (int i = 0; i < 4; ++i)
    s64[i] = (uint64_t)st32[2*i] | ((uint64_t)st32[2*i+1] << 32);

  // ---- PCG64 (setseq 128, XSL-RR output, step-then-output)
  typedef unsigned __int128 u128;
  const u128 MUL = ((u128)2549297995355413924ull << 64) | (u128)4865540595714422341ull;
  u128 inc   = (((((u128)s64[2]) << 64) | (u128)s64[3]) << 1) | 1;
  u128 state = inc;                                 // state=0; step
  state += (((u128)s64[0]) << 64) | (u128)s64[1];   // += initstate
  state = state * MUL + inc;                        // step

  bool has32 = false; uint32_t buf32 = 0;
  auto next32 = [&]() -> uint32_t {
    if (has32) { has32 = false; return buf32; }
    state = state * MUL + inc;
    uint64_t hi = (uint64_t)(state >> 64), lo = (uint64_t)state;
    uint64_t x = hi ^ lo;
    unsigned rot = (unsigned)(state >> 122);
    uint64_t v = (x >> rot) | (x << ((64u - rot) & 63u));
    has32 = true; buf32 = (uint32_t)(v >> 32);
    return (uint32_t)v;
  };

  // ---- Floyd's algorithm, hash table size 512 (mask from 1.2*409=490)
  for (int j = NN - INNER; j < NN; ++j) {
    uint32_t rng = (uint32_t)j, rng_excl = rng + 1u;
    uint64_t m = (uint64_t)next32() * (uint64_t)rng_excl;
    uint32_t leftover = (uint32_t)m;
    if (leftover < rng_excl) {
      uint32_t threshold = (0xFFFFFFFFu - rng) % rng_excl;
      while (leftover < threshold) {
        m = (uint64_t)next32() * (uint64_t)rng_excl;
        leftover = (uint32_t)m;
      }
    }
    uint64_t val = m >> 32;
    uint32_t loc = (uint32_t)val & 511u;
    while (hs[loc] != ~0ull && hs[loc] != val) loc = (loc + 1u) & 511u;
    uint64_t chosen;
    if (hs[loc] == ~0ull) { hs[loc] = val; chosen = val; }
    else                  { hs[loc] = (uint64_t)j; chosen = (uint64_t)j; }
    out[j - (NN - INNER)] = (int)chosen;
  }
}

// ======================= generic 32x32-tiled transpose: in(R,Cc) -> out(Cc,R)
__global__ void transpose_k(const float* __restrict__ in, float* __restrict__ out,
                            int R, int Cc, long long inB, long long outB) {
  __shared__ float t[32][33];
  const float* ib = in  + (long long)blockIdx.z * inB;
  float*       ob = out + (long long)blockIdx.z * outB;
  int c0 = blockIdx.x * 32, r0 = blockIdx.y * 32;
  int tx = threadIdx.x, ty = threadIdx.y;   // 32 x 8
  for (int i = 0; i < 32; i += 8) {
    int r = r0 + ty + i, c = c0 + tx;
    if (r < R && c < Cc) t[ty + i][tx] = ib[(size_t)r * Cc + c];
  }
  __syncthreads();
  for (int i = 0; i < 32; i += 8) {
    int c = c0 + ty + i, r = r0 + tx;
    if (r < R && c < Cc) ob[(size_t)c * R + r] = t[tx][ty + i];
  }
}

// ======================= 3-NN over S=2048, inverse-distance weights
__global__ __launch_bounds__(256) void knn_k(const float* __restrict__ xyz1,
                                             const float* __restrict__ xyz2,
                                             int* __restrict__ idx3,
                                             float* __restrict__ w3) {
  __shared__ float X[SS], Y[SS], Z[SS], SSQ[SS];
  int b = blockIdx.y;
  const float* x2 = xyz2 + (size_t)b * SS * 3;
  for (int i = threadIdx.x; i < SS; i += 256) {
    float x = x2[i*3], y = x2[i*3+1], z = x2[i*3+2];
    X[i] = x; Y[i] = y; Z[i] = z; SSQ[i] = x*x + y*y + z*z;
  }
  __syncthreads();
  int n = blockIdx.x * 256 + threadIdx.x;
  const float* p = xyz1 + ((size_t)b * NN + n) * 3;
  float px = p[0], py = p[1], pz = p[2];
  float ss1 = px*px + py*py + pz*pz;
  float d0 = 3.4e38f, d1 = 3.4e38f, d2 = 3.4e38f;
  int   i0 = 0, i1 = 0, i2 = 0;
  for (int s = 0; s < SS; ++s) {
    float d = (ss1 + SSQ[s]) - 2.0f * (px*X[s] + py*Y[s] + pz*Z[s]);
    if (d < d2) {
      if (d < d1) {
        d2 = d1; i2 = i1;
        if (d < d0) { d1 = d0; i1 = i0; d0 = d; i0 = s; }
        else        { d1 = d;  i1 = s; }
      } else { d2 = d; i2 = s; }
    }
  }
  d0 = fmaxf(d0, 1e-10f); d1 = fmaxf(d1, 1e-10f); d2 = fmaxf(d2, 1e-10f);
  float w0 = 1.f/d0, w1 = 1.f/d1, w2 = 1.f/d2;
  float ws = w0 + w1 + w2;
  size_t o = (size_t)b * NN + n;
  idx3[o*3] = i0; idx3[o*3+1] = i1; idx3[o*3+2] = i2;
  w3[o*3] = w0/ws; w3[o*3+1] = w1/ws; w3[o*3+2] = w2/ws;
}

// ======================= gather interpolated features (256ch) + preds (21ch)
__global__ __launch_bounds__(256) void interp_k(const float* __restrict__ p2t,
                                                const float* __restrict__ lastpred,
                                                const int* __restrict__ idx3,
                                                const float* __restrict__ w3,
                                                float* __restrict__ interp,
                                                float* __restrict__ preds) {
  int b = blockIdx.y, n = blockIdx.x;
  size_t o = (size_t)b * NN + n;
  int i0 = idx3[o*3], i1 = idx3[o*3+1], i2 = idx3[o*3+2];
  float w0 = w3[o*3], w1 = w3[o*3+1], w2 = w3[o*3+2];
  const float* pb = p2t + (size_t)b * SS * 256;
  int c = threadIdx.x;
  interp[o*256 + c] = w0 * pb[(size_t)i0*256 + c]
                    + w1 * pb[(size_t)i1*256 + c]
                    + w2 * pb[(size_t)i2*256 + c];
  if (c < CLS) {
    const float* lp = lastpred + (size_t)b * SS * CLS;
    preds[o*CLS + c] = w0 * lp[i0*CLS + c] + w1 * lp[i1*CLS + c] + w2 * lp[i2*CLS + c];
  }
}

// ======================= generic f32 GEMM: C(M,Nc) = A(M,K) * W^T, fused epilogue
struct GemmP {
  const float* A;  const float* A2; const float* W;
  const float* bias; const float* bng; const float* bnb; const float* res;
  float* C;
  int M, Nc, K, K1, lda1, A1T, WT, act;   // act: 0 none, 1 relu, 2 leaky(0.2)
};

__global__ __launch_bounds__(256) void gemm_k(GemmP p) {
  __shared__ float As[16][68];
  __shared__ float Ws[16][68];
  const int bm = blockIdx.y * 64, bn = blockIdx.x * 64;
  const int tid = threadIdx.x;
  const int tx = tid & 15, ty = tid >> 4;
  float acc[4][4] = {{0.f,0.f,0.f,0.f},{0.f,0.f,0.f,0.f},{0.f,0.f,0.f,0.f},{0.f,0.f,0.f,0.f}};
  const int K2 = p.K - p.K1;
  for (int k0 = 0; k0 < p.K; k0 += 16) {
    if (p.A1T && k0 < p.K1) {            // A part-1 stored (K1, lda1), m contiguous
      const int mm = tid & 63, kb = tid >> 6;
      #pragma unroll
      for (int kk = kb; kk < 16; kk += 4) {
        const int gm = bm + mm, gk = k0 + kk;
        As[kk][mm] = (gm < p.M && gk < p.K1) ? p.A[(size_t)gk * p.lda1 + gm] : 0.f;
      }
    } else {                             // row-major A (or A2 for gk>=K1)
      const int kk = tid & 15, mb = tid >> 4;
      #pragma unroll
      for (int mm = mb; mm < 64; mm += 16) {
        const int gm = bm + mm, gk = k0 + kk;
        float v = 0.f;
        if (gm < p.M && gk < p.K)
          v = (gk < p.K1) ? p.A[(size_t)gm * p.K1 + gk]
                          : p.A2[(size_t)gm * K2 + (gk - p.K1)];
        As[kk][mm] = v;
      }
    }
    if (p.WT) {                          // W stored (K, Nc)
      const int nn = tid & 63, kb = tid >> 6;
      #pragma unroll
      for (int kk = kb; kk < 16; kk += 4) {
        const int gn = bn + nn, gk = k0 + kk;
        Ws[kk][nn] = (gn < p.Nc && gk < p.K) ? p.W[(size_t)gk * p.Nc + gn] : 0.f;
      }
    } else {                             // W stored (Nc, K)
      const int kk = tid & 15, nb = tid >> 4;
      #pragma unroll
      for (int nn = nb; nn < 64; nn += 16) {
        const int gn = bn + nn, gk = k0 + kk;
        Ws[kk][nn] = (gn < p.Nc && gk < p.K) ? p.W[(size_t)gn * p.K + gk] : 0.f;
      }
    }
    __syncthreads();
    #pragma unroll
    for (int kk = 0; kk < 16; ++kk) {
      const float4 av = *(const float4*)&As[kk][ty * 4];
      const float4 bv = *(const float4*)&Ws[kk][tx * 4];
      acc[0][0] += av.x*bv.x; acc[0][1] += av.x*bv.y; acc[0][2] += av.x*bv.z; acc[0][3] += av.x*bv.w;
      acc[1][0] += av.y*bv.x; acc[1][1] += av.y*bv.y; acc[1][2] += av.y*bv.z; acc[1][3] += av.y*bv.w;
      acc[2][0] += av.z*bv.x; acc[2][1] += av.z*bv.y; acc[2][2] += av.z*bv.z; acc[2][3] += av.z*bv.w;
      acc[3][0] += av.w*bv.x; acc[3][1] += av.w*bv.y; acc[3][2] += av.w*bv.z; acc[3][3] += av.w*bv.w;
    }
    __syncthreads();
  }
  const float bnden = sqrtf(1.0f + 1e-5f);
  #pragma unroll
  for (int i = 0; i < 4; ++i) {
    const int r = bm + ty * 4 + i;
    if (r >= p.M) break;
    #pragma unroll
    for (int j = 0; j < 4; ++j) {
      const int c = bn + tx * 4 + j;
      if (c >= p.Nc) continue;
      float v = acc[i][j];
      if (p.bias) v += p.bias[c];
      if (p.bng)  v = v * (p.bng[c] / bnden) + p.bnb[c];
      if (p.res)  v += p.res[(size_t)r * p.Nc + c];
      if (p.act == 1)      v = fmaxf(v, 0.f);
      else if (p.act == 2) v = (v >= 0.f) ? v : 0.2f * v;
      p.C[(size_t)r * p.Nc + c] = v;
    }
  }
}

// ======================= diff[b,n] = sum_k sum_c (flat[idx1]-xt)^2
__global__ __launch_bounds__(128) void diff_k(const float* __restrict__ xt,
                                              const int* __restrict__ idx1,
                                              float* __restrict__ diff) {
  __shared__ float r2[2];
  int bn = blockIdx.x;
  int c  = threadIdx.x;           // 0..127
  float xc = xt[(size_t)bn * CO + c];
  const int* id = idx1 + (size_t)bn * KNB;
  float acc = 0.f;
  #pragma unroll
  for (int k = 0; k < KNB; ++k) {
    int ix = id[k];
    float d = xt[(size_t)ix * CO + c] - xc;
    acc += d * d;
  }
  for (int o = 32; o; o >>= 1) acc += __shfl_xor(acc, o);
  if ((c & 63) == 0) r2[c >> 6] = acc;
  __syncthreads();
  if (c == 0) diff[bn] = r2[0] + r2[1];
}

// ======================= per-batch top-1638 via full bitonic sort + append inner
// key = (valbits<<32)|(8191-i): diff>=0 so float bits are order-monotone;
// desc sort => desc value, tie -> smaller index first (matches lax.top_k).
__global__ __launch_bounds__(1024) void topk_k(const float* __restrict__ diff,
                                               const int* __restrict__ inner,
                                               int* __restrict__ Hidx) {
  __shared__ uint64_t kv[NN];
  int b = blockIdx.x, tid = threadIdx.x;
  for (int i = tid; i < NN; i += 1024) {
    uint32_t bits = __float_as_uint(diff[(size_t)b * NN + i]);
    kv[i] = ((uint64_t)bits << 32) | (uint64_t)(NN - 1 - i);
  }
  __syncthreads();
  for (int k = 2; k <= NN; k <<= 1) {
    for (int j = k >> 1; j > 0; j >>= 1) {
      for (int t = tid; t < NN/2; t += 1024) {
        int i = ((t & ~(j - 1)) << 1) | (t & (j - 1));
        int q = i | j;
        uint64_t a = kv[i], c = kv[q];
        bool desc = ((i & k) == 0);
        bool sw = desc ? (a < c) : (a > c);
        if (sw) { kv[i] = c; kv[q] = a; }
      }
      __syncthreads();
    }
  }
  for (int t = tid; t < OUTER; t += 1024)
    Hidx[b * HH + t] = NN - 1 - (int)(kv[t] & 0xFFFFFFFFull);
  if (tid < INNER) Hidx[b * HH + OUTER + tid] = inner[tid];
}

// ======================= gather Hp rows: [xt(128) | preds(21)] at H_idx
__global__ void hpgather_k(const float* __restrict__ xt,
                           const float* __restrict__ preds,
                           const int* __restrict__ Hidx,
                           float* __restrict__ HpA) {
  int b = blockIdx.y, h = blockIdx.x;
  int src = Hidx[b * HH + h];
  size_t srow = (size_t)b * NN + src;
  size_t drow = (size_t)b * HH + h;
  int t = threadIdx.x;
  if (t < CO)            HpA[drow * 149 + t] = xt[srow * CO + t];
  else if (t < CO + CLS) HpA[drow * 149 + t] = preds[srow * CLS + (t - CO)];
}

// ======================= in-place row softmax (cols <= 2047)
__global__ __launch_bounds__(256) void row_softmax_k(float* __restrict__ f, int cols) {
  __shared__ float buf[2048];
  __shared__ float red[4];
  size_t r = blockIdx.x;
  float* row = f + r * (size_t)cols;
  int tid = threadIdx.x;
  float m = -3.4e38f;
  for (int c = tid; c < cols; c += 256) { float v = row[c]; buf[c] = v; m = fmaxf(m, v); }
  for (int o = 32; o; o >>= 1) m = fmaxf(m, __shfl_xor(m, o));
  if ((tid & 63) == 0) red[tid >> 6] = m;
  __syncthreads();
  m = fmaxf(fmaxf(red[0], red[1]), fmaxf(red[2], red[3]));
  __syncthreads();
  float s = 0.f;
  for (int c = tid; c < cols; c += 256) { float e = expf(buf[c] - m); buf[c] = e; s += e; }
  for (int o = 32; o; o >>= 1) s += __shfl_xor(s, o);
  if ((tid & 63) == 0) red[tid >> 6] = s;
  __syncthreads();
  s = red[0] + red[1] + red[2] + red[3];
  float inv = 1.0f / s;
  for (int c = tid; c < cols; c += 256) row[c] = buf[c] * inv;
}

// ======================= per-row log_softmax over 21 logits -> d_out part 2
__global__ __launch_bounds__(256) void logsm_k(const float* __restrict__ logits,
                                               float* __restrict__ out) {
  int r = blockIdx.x * 256 + threadIdx.x;
  if (r >= BB * NN) return;
  const float* l = logits + (size_t)r * CLS;
  float*       o = out    + (size_t)r * CLS;
  float m = l[0];
  #pragma unroll
  for (int i = 1; i < CLS; ++i) m = fmaxf(m, l[i]);
  float s = 0.f;
  #pragma unroll
  for (int i = 0; i < CLS; ++i) s += expf(l[i] - m);
  float lse = m + logf(s);
  #pragma unroll
  for (int i = 0; i < CLS; ++i) o[i] = l[i] - lse;
}

static inline dim3 ggrid(int M, int Nc) { return dim3((Nc + 63) / 64, (M + 63) / 64); }

} // anonymous namespace

// ===========================================================================
extern "C" void kernel_launch(void* const* d_in, const int* in_sizes, int n_in,
                              void* d_out, int out_size, void* d_ws, size_t ws_size,
                              hipStream_t stream) {
  const float* xyz1    = (const float*)d_in[0];
  const float* xyz2    = (const float*)d_in[1];
  const float* points1 = (const float*)d_in[2];
  const float* points2 = (const float*)d_in[3];
  /* d_in[4] rgb1 unused */
  const float* lastpred= (const float*)d_in[5];
  const float* w_mlp0  = (const float*)d_in[6];
  const float* b_mlp0  = (const float*)d_in[7];
  const float* g_bn0   = (const float*)d_in[8];
  const float* be_bn0  = (const float*)d_in[9];
  const float* w_mlp1  = (const float*)d_in[10];
  const float* b_mlp1  = (const float*)d_in[11];
  const float* g_bn1   = (const float*)d_in[12];
  const float* be_bn1  = (const float*)d_in[13];
  const float* w_h     = (const float*)d_in[14];
  const float* g_hbn   = (const float*)d_in[15];
  const float* be_hbn  = (const float*)d_in[16];
  const float* w_outm  = (const float*)d_in[17];
  const float* g_obn   = (const float*)d_in[18];
  const float* be_obn  = (const float*)d_in[19];
  const float* w_g     = (const float*)d_in[20];
  const float* b_g     = (const float*)d_in[21];
  const float* w_theta = (const float*)d_in[22];
  const float* b_theta = (const float*)d_in[23];
  const float* w_phi   = (const float*)d_in[24];
  const float* b_phi   = (const float*)d_in[25];
  const float* w_W     = (const float*)d_in[26];
  const float* b_W     = (const float*)d_in[27];
  const float* g_Wbn   = (const float*)d_in[28];
  const float* be_Wbn  = (const float*)d_in[29];
  const float* w5      = (const float*)d_in[30];
  const float* b5      = (const float*)d_in[31];
  const float* g_bn5   = (const float*)d_in[32];
  const float* be_bn5  = (const float*)d_in[33];
  const float* w6      = (const float*)d_in[34];
  const float* b6      = (const float*)d_in[35];
  const int*   idx_1   = (const int*)d_in[36];
  /* d_in[37] = k (==20) */

  float* out0 = (float*)d_out;                         // (B,128,N)
  float* out1 = out0 + (size_t)BB * CO * NN;           // (B,N,21)

  // ---------------- workspace layout (aliased; ~113.4 MB total)
  char* base = (char*)d_ws;
  size_t off = 0;
  auto alloc = [&](size_t bytes) -> char* {
    char* p = base + off;
    off += (bytes + 255) & ~(size_t)255;
    return p;
  };
  int*   inner  = (int*)  alloc((size_t)INNER * 4);
  int*   idx3   = (int*)  alloc((size_t)BB * NN * 3 * 4);
  float* w3     = (float*)alloc((size_t)BB * NN * 3 * 4);
  float* diff   = (float*)alloc((size_t)BB * NN * 4);
  int*   Hidx   = (int*)  alloc((size_t)BB * HH * 4);
  float* preds  = (float*)alloc((size_t)BB * NN * CLS * 4);        // later: logits
  float* HpA    = (float*)alloc((size_t)BB * HH * 149 * 4);
  float* Hp2    = (float*)alloc((size_t)BB * HH * CO * 4);
  float* gx     = (float*)alloc((size_t)BB * HH * CO * 4);
  float* phiT   = (float*)alloc((size_t)BB * HH * CO * 4);
  float* xt     = (float*)alloc((size_t)BB * NN * CO * 4);
  char*  RI     =         alloc((size_t)BB * NN * 256 * 4);        // 32MB region
  char*  RX     =         alloc((size_t)BB * NN * 256 * 4);        // 32MB region
  float* p2t    = (float*)alloc((size_t)BB * SS * 256 * 4);
  if (off > ws_size) return;   // insufficient scratch -> output stays zero (diagnostic)

  float* interp = (float*)RI;                                   // steps 4-5
  float* theta  = (float*)RI;                                   // steps 13-14
  float* yattn  = (float*)(RI + (size_t)BB * NN * CO * 4);      // steps 14-15
  float* x2     = (float*)RX;                                   // steps 5-6
  float* fbuf   = (float*)RX;                                   // attention chunks
  float* zbuf   = (float*)RX;                                   // steps 15-16
  float* h5     = (float*)RX;                                   // steps 18-19
  float* npo    = (float*)(RX + (size_t)BB * NN * CO * 4);      // steps 16-18
  float* logits = preds;                                        // step 19

  // 1. inner indices (numpy RNG replication)
  inner_idx_k<<<1, 512, 0, stream>>>(inner);

  // 2. transpose points2 (B,256,S) -> p2t (B,S,256)
  transpose_k<<<dim3(SS/32, 256/32, BB), dim3(32, 8), 0, stream>>>(
      points2, p2t, 256, SS, (long long)256 * SS, (long long)SS * 256);

  // 3. 3-NN
  knn_k<<<dim3(NN/256, BB), 256, 0, stream>>>(xyz1, xyz2, idx3, w3);

  // 4. interpolate features + lastpred
  interp_k<<<dim3(NN, BB), 256, 0, stream>>>(p2t, lastpred, idx3, w3, interp, preds);

  // 5. mlp0: relu(bn0(W0*[points1^T | interp] + b0))   (per batch: A1 transposed)
  for (int b = 0; b < BB; ++b) {
    GemmP p{};
    p.A = points1 + (size_t)b * 256 * NN; p.A1T = 1; p.lda1 = NN; p.K1 = 256;
    p.A2 = interp + (size_t)b * NN * 256;
    p.W = w_mlp0; p.WT = 0;
    p.bias = b_mlp0; p.bng = g_bn0; p.bnb = be_bn0; p.res = nullptr;
    p.C = x2 + (size_t)b * NN * 256;
    p.M = NN; p.Nc = 256; p.K = 512; p.act = 1;
    gemm_k<<<ggrid(NN, 256), 256, 0, stream>>>(p);
  }

  // 6. mlp1 -> xt (B*N, 128)
  {
    GemmP p{};
    p.A = x2; p.K1 = 256; p.W = w_mlp1;
    p.bias = b_mlp1; p.bng = g_bn1; p.bnb = be_bn1;
    p.C = xt; p.M = BB * NN; p.Nc = CO; p.K = 256; p.act = 1;
    gemm_k<<<ggrid(BB * NN, CO), 256, 0, stream>>>(p);
  }

  // 7. KNN feature variance score
  diff_k<<<BB * NN, 128, 0, stream>>>(xt, idx_1, diff);

  // 8. per-batch top-1638 (+ append inner 409)
  topk_k<<<BB, 1024, 0, stream>>>(diff, inner, Hidx);

  // 9. gather Hp rows (B*H, 149)
  hpgather_k<<<dim3(HH, BB), 192, 0, stream>>>(xt, preds, Hidx, HpA);

  // 10. conv_h: leaky(bn_h(W_h * Hp))    (no bias)
  {
    GemmP p{};
    p.A = HpA; p.K1 = 149; p.W = w_h;
    p.bng = g_hbn; p.bnb = be_hbn;
    p.C = Hp2; p.M = BB * HH; p.Nc = CO; p.K = 149; p.act = 2;
    gemm_k<<<ggrid(BB * HH, CO), 256, 0, stream>>>(p);
  }
  // 11. g_x
  {
    GemmP p{};
    p.A = Hp2; p.K1 = CO; p.W = w_g; p.bias = b_g;
    p.C = gx; p.M = BB * HH; p.Nc = CO; p.K = CO; p.act = 0;
    gemm_k<<<ggrid(BB * HH, CO), 256, 0, stream>>>(p);
  }
  // 12. phi (stored transposed: (B*H, 128))
  {
    GemmP p{};
    p.A = Hp2; p.K1 = CO; p.W = w_phi; p.bias = b_phi;
    p.C = phiT; p.M = BB * HH; p.Nc = CO; p.K = CO; p.act = 0;
    gemm_k<<<ggrid(BB * HH, CO), 256, 0, stream>>>(p);
  }
  // 13. theta
  {
    GemmP p{};
    p.A = xt; p.K1 = CO; p.W = w_theta; p.bias = b_theta;
    p.C = theta; p.M = BB * NN; p.Nc = CO; p.K = CO; p.act = 0;
    gemm_k<<<ggrid(BB * NN, CO), 256, 0, stream>>>(p);
  }

  // 14. attention, chunked over 2048 query rows: f = theta*phi^T; softmax; y = a*g_x
  for (int b = 0; b < BB; ++b) {
    for (int ch = 0; ch < NN / 2048; ++ch) {
      const float* Ath = theta + ((size_t)b * NN + (size_t)ch * 2048) * CO;
      {
        GemmP p{};
        p.A = Ath; p.K1 = CO; p.W = phiT + (size_t)b * HH * CO;
        p.C = fbuf; p.M = 2048; p.Nc = HH; p.K = CO; p.act = 0;
        gemm_k<<<ggrid(2048, HH), 256, 0, stream>>>(p);
      }
      row_softmax_k<<<2048, 256, 0, stream>>>(fbuf, HH);
      {
        GemmP p{};
        p.A = fbuf; p.K1 = HH; p.W = gx + (size_t)b * HH * CO; p.WT = 1;
        p.C = yattn + ((size_t)b * NN + (size_t)ch * 2048) * CO;
        p.M = 2048; p.Nc = CO; p.K = HH; p.act = 0;
        gemm_k<<<ggrid(2048, CO), 256, 0, stream>>>(p);
      }
    }
  }

  // 15. z = bn_W(W_W*y + b_W) + x   (residual)
  {
    GemmP p{};
    p.A = yattn; p.K1 = CO; p.W = w_W; p.bias = b_W;
    p.bng = g_Wbn; p.bnb = be_Wbn; p.res = xt;
    p.C = zbuf; p.M = BB * NN; p.Nc = CO; p.K = CO; p.act = 0;
    gemm_k<<<ggrid(BB * NN, CO), 256, 0, stream>>>(p);
  }
  // 16. new_points_out = leaky(bn_o(W_outm*z))   (no bias)
  {
    GemmP p{};
    p.A = zbuf; p.K1 = CO; p.W = w_outm;
    p.bng = g_obn; p.bnb = be_obn;
    p.C = npo; p.M = BB * NN; p.Nc = CO; p.K = CO; p.act = 2;
    gemm_k<<<ggrid(BB * NN, CO), 256, 0, stream>>>(p);
  }
  // 17. transpose npo (B,N,128) -> d_out part 1 (B,128,N)
  transpose_k<<<dim3(CO/32, NN/32, BB), dim3(32, 8), 0, stream>>>(
      npo, out0, NN, CO, (long long)NN * CO, (long long)CO * NN);

  // 18. h5 = relu(bn5(W5*npo + b5))
  {
    GemmP p{};
    p.A = npo; p.K1 = CO; p.W = w5; p.bias = b5;
    p.bng = g_bn5; p.bnb = be_bn5;
    p.C = h5; p.M = BB * NN; p.Nc = 32; p.K = CO; p.act = 1;
    gemm_k<<<ggrid(BB * NN, 32), 256, 0, stream>>>(p);
  }
  // 19. logits = W6*h5 + b6
  {
    GemmP p{};
    p.A = h5; p.K1 = 32; p.W = w6; p.bias = b6;
    p.C = logits; p.M = BB * NN; p.Nc = CLS; p.K = 32; p.act = 0;
    gemm_k<<<ggrid(BB * NN, CLS), 256, 0, stream>>>(p);
  }
  // 20. log_softmax -> d_out part 2
  logsm_k<<<(BB * NN + 255) / 256, 256, 0, stream>>>(logits, out1);
}

// Round 2
// 1549.973 us; speedup vs baseline: 4.4039x; 4.4039x over previous
//
#include <hip/hip_runtime.h>
#include <stdint.h>
#include <math.h>

// ---------------------------------------------------------------------------
// IAF_PointNetFeaturePropagation: f32 pipeline, fused flash attention.
// B=4, N=8192, S=2048, K=20, D1=D2=256, CO=128, CLS=21, H=1638+409=2047
// ---------------------------------------------------------------------------

namespace {

constexpr int BB   = 4;
constexpr int NN   = 8192;
constexpr int SS   = 2048;
constexpr int KNB  = 20;
constexpr int CO   = 128;
constexpr int CLS  = 21;
constexpr int HH   = 2047;
constexpr int OUTER= 1638;
constexpr int INNER= 409;

// ======================= numpy default_rng(0).choice(8192,409,replace=False)
__global__ __launch_bounds__(512) void inner_idx_k(int* __restrict__ out) {
  __shared__ uint64_t hs[512];
  hs[threadIdx.x] = ~0ull;
  __syncthreads();
  if (threadIdx.x != 0) return;

  uint32_t pool[4];
  uint32_t hc = 0x43b0d7e5u;
  auto hashmix = [&hc](uint32_t v) -> uint32_t {
    v ^= hc; hc *= 0x931e8875u; v *= hc; v ^= v >> 16; return v;
  };
  auto mixf = [](uint32_t x, uint32_t y) -> uint32_t {
    uint32_t r = x * 0xca01f9ddu; r ^= y * 0x4973f715u; r ^= r >> 16; return r;
  };
  pool[0] = hashmix(0u); pool[1] = hashmix(0u);
  pool[2] = hashmix(0u); pool[3] = hashmix(0u);
  for (int s = 0; s < 4; ++s)
    for (int d = 0; d < 4; ++d)
      if (s != d) pool[d] = mixf(pool[d], hashmix(pool[s]));

  uint32_t st32[8];
  uint32_t hb = 0x8b51f9ddu;
  for (int i = 0; i < 8; ++i) {
    uint32_t dv = pool[i & 3];
    dv ^= hb; hb *= 0x58f38dedu; dv *= hb; dv ^= dv >> 16;
    st32[i] = dv;
  }
  uint64_t s64[4];
  for (int i = 0; i < 4; ++i)
    s64[i] = (uint64_t)st32[2*i] | ((uint64_t)st32[2*i+1] << 32);

  typedef unsigned __int128 u128;
  const u128 MUL = ((u128)2549297995355413924ull << 64) | (u128)4865540595714422341ull;
  u128 inc   = (((((u128)s64[2]) << 64) | (u128)s64[3]) << 1) | 1;
  u128 state = inc;
  state += (((u128)s64[0]) << 64) | (u128)s64[1];
  state = state * MUL + inc;

  bool has32 = false; uint32_t buf32 = 0;
  auto next32 = [&]() -> uint32_t {
    if (has32) { has32 = false; return buf32; }
    state = state * MUL + inc;
    uint64_t hi = (uint64_t)(state >> 64), lo = (uint64_t)state;
    uint64_t x = hi ^ lo;
    unsigned rot = (unsigned)(state >> 122);
    uint64_t v = (x >> rot) | (x << ((64u - rot) & 63u));
    has32 = true; buf32 = (uint32_t)(v >> 32);
    return (uint32_t)v;
  };

  for (int j = NN - INNER; j < NN; ++j) {
    uint32_t rng = (uint32_t)j, rng_excl = rng + 1u;
    uint64_t m = (uint64_t)next32() * (uint64_t)rng_excl;
    uint32_t leftover = (uint32_t)m;
    if (leftover < rng_excl) {
      uint32_t threshold = (0xFFFFFFFFu - rng) % rng_excl;
      while (leftover < threshold) {
        m = (uint64_t)next32() * (uint64_t)rng_excl;
        leftover = (uint32_t)m;
      }
    }
    uint64_t val = m >> 32;
    uint32_t loc = (uint32_t)val & 511u;
    while (hs[loc] != ~0ull && hs[loc] != val) loc = (loc + 1u) & 511u;
    uint64_t chosen;
    if (hs[loc] == ~0ull) { hs[loc] = val; chosen = val; }
    else                  { hs[loc] = (uint64_t)j; chosen = (uint64_t)j; }
    out[j - (NN - INNER)] = (int)chosen;
  }
}

// ======================= generic 32x32-tiled transpose
__global__ void transpose_k(const float* __restrict__ in, float* __restrict__ out,
                            int R, int Cc, long long inB, long long outB) {
  __shared__ float t[32][33];
  const float* ib = in  + (long long)blockIdx.z * inB;
  float*       ob = out + (long long)blockIdx.z * outB;
  int c0 = blockIdx.x * 32, r0 = blockIdx.y * 32;
  int tx = threadIdx.x, ty = threadIdx.y;
  for (int i = 0; i < 32; i += 8) {
    int r = r0 + ty + i, c = c0 + tx;
    if (r < R && c < Cc) t[ty + i][tx] = ib[(size_t)r * Cc + c];
  }
  __syncthreads();
  for (int i = 0; i < 32; i += 8) {
    int c = c0 + ty + i, r = r0 + tx;
    if (r < R && c < Cc) ob[(size_t)c * R + r] = t[tx][ty + i];
  }
}

// ======================= 3-NN over S=2048
__global__ __launch_bounds__(256) void knn_k(const float* __restrict__ xyz1,
                                             const float* __restrict__ xyz2,
                                             int* __restrict__ idx3,
                                             float* __restrict__ w3) {
  __shared__ float X[SS], Y[SS], Z[SS], SSQ[SS];
  int b = blockIdx.y;
  const float* x2 = xyz2 + (size_t)b * SS * 3;
  for (int i = threadIdx.x; i < SS; i += 256) {
    float x = x2[i*3], y = x2[i*3+1], z = x2[i*3+2];
    X[i] = x; Y[i] = y; Z[i] = z; SSQ[i] = x*x + y*y + z*z;
  }
  __syncthreads();
  int n = blockIdx.x * 256 + threadIdx.x;
  const float* p = xyz1 + ((size_t)b * NN + n) * 3;
  float px = p[0], py = p[1], pz = p[2];
  float ss1 = px*px + py*py + pz*pz;
  float d0 = 3.4e38f, d1 = 3.4e38f, d2 = 3.4e38f;
  int   i0 = 0, i1 = 0, i2 = 0;
  for (int s = 0; s < SS; ++s) {
    float d = (ss1 + SSQ[s]) - 2.0f * (px*X[s] + py*Y[s] + pz*Z[s]);
    if (d < d2) {
      if (d < d1) {
        d2 = d1; i2 = i1;
        if (d < d0) { d1 = d0; i1 = i0; d0 = d; i0 = s; }
        else        { d1 = d;  i1 = s; }
      } else { d2 = d; i2 = s; }
    }
  }
  d0 = fmaxf(d0, 1e-10f); d1 = fmaxf(d1, 1e-10f); d2 = fmaxf(d2, 1e-10f);
  float w0 = 1.f/d0, w1 = 1.f/d1, w2 = 1.f/d2;
  float ws = w0 + w1 + w2;
  size_t o = (size_t)b * NN + n;
  idx3[o*3] = i0; idx3[o*3+1] = i1; idx3[o*3+2] = i2;
  w3[o*3] = w0/ws; w3[o*3+1] = w1/ws; w3[o*3+2] = w2/ws;
}

// ======================= interpolation gather
__global__ __launch_bounds__(256) void interp_k(const float* __restrict__ p2t,
                                                const float* __restrict__ lastpred,
                                                const int* __restrict__ idx3,
                                                const float* __restrict__ w3,
                                                float* __restrict__ interp,
                                                float* __restrict__ preds) {
  int b = blockIdx.y, n = blockIdx.x;
  size_t o = (size_t)b * NN + n;
  int i0 = idx3[o*3], i1 = idx3[o*3+1], i2 = idx3[o*3+2];
  float w0 = w3[o*3], w1 = w3[o*3+1], w2 = w3[o*3+2];
  const float* pb = p2t + (size_t)b * SS * 256;
  int c = threadIdx.x;
  interp[o*256 + c] = w0 * pb[(size_t)i0*256 + c]
                    + w1 * pb[(size_t)i1*256 + c]
                    + w2 * pb[(size_t)i2*256 + c];
  if (c < CLS) {
    const float* lp = lastpred + (size_t)b * SS * CLS;
    preds[o*CLS + c] = w0 * lp[i0*CLS + c] + w1 * lp[i1*CLS + c] + w2 * lp[i2*CLS + c];
  }
}

// ======================= generic f32 GEMM with fused epilogue (z-batched)
struct GemmP {
  const float* A;  const float* A2; const float* W;
  const float* bias; const float* bng; const float* bnb; const float* res;
  float* C;
  int M, Nc, K, K1, lda1, A1T, WT, act;
  long long zA, zA2, zC;        // element strides for blockIdx.z batching
};

__global__ __launch_bounds__(256) void gemm_k(GemmP p) {
  __shared__ float As[16][68];
  __shared__ float Ws[16][68];
  const float* Ab  = p.A  + (size_t)blockIdx.z * p.zA;
  const float* A2b = p.A2 + (size_t)blockIdx.z * p.zA2;
  float*       Cb  = p.C  + (size_t)blockIdx.z * p.zC;
  const float* Rb  = p.res ? p.res + (size_t)blockIdx.z * p.zC : nullptr;
  const int bm = blockIdx.y * 64, bn = blockIdx.x * 64;
  const int tid = threadIdx.x;
  const int tx = tid & 15, ty = tid >> 4;
  float acc[4][4] = {{0.f,0.f,0.f,0.f},{0.f,0.f,0.f,0.f},{0.f,0.f,0.f,0.f},{0.f,0.f,0.f,0.f}};
  const int K2 = p.K - p.K1;
  for (int k0 = 0; k0 < p.K; k0 += 16) {
    if (p.A1T && k0 < p.K1) {
      const int mm = tid & 63, kb = tid >> 6;
      #pragma unroll
      for (int kk = kb; kk < 16; kk += 4) {
        const int gm = bm + mm, gk = k0 + kk;
        As[kk][mm] = (gm < p.M && gk < p.K1) ? Ab[(size_t)gk * p.lda1 + gm] : 0.f;
      }
    } else {
      const int kk = tid & 15, mb = tid >> 4;
      #pragma unroll
      for (int mm = mb; mm < 64; mm += 16) {
        const int gm = bm + mm, gk = k0 + kk;
        float v = 0.f;
        if (gm < p.M && gk < p.K)
          v = (gk < p.K1) ? Ab[(size_t)gm * p.K1 + gk]
                          : A2b[(size_t)gm * K2 + (gk - p.K1)];
        As[kk][mm] = v;
      }
    }
    if (p.WT) {
      const int nn = tid & 63, kb = tid >> 6;
      #pragma unroll
      for (int kk = kb; kk < 16; kk += 4) {
        const int gn = bn + nn, gk = k0 + kk;
        Ws[kk][nn] = (gn < p.Nc && gk < p.K) ? p.W[(size_t)gk * p.Nc + gn] : 0.f;
      }
    } else {
      const int kk = tid & 15, nb = tid >> 4;
      #pragma unroll
      for (int nn = nb; nn < 64; nn += 16) {
        const int gn = bn + nn, gk = k0 + kk;
        Ws[kk][nn] = (gn < p.Nc && gk < p.K) ? p.W[(size_t)gn * p.K + gk] : 0.f;
      }
    }
    __syncthreads();
    #pragma unroll
    for (int kk = 0; kk < 16; ++kk) {
      const float4 av = *(const float4*)&As[kk][ty * 4];
      const float4 bv = *(const float4*)&Ws[kk][tx * 4];
      acc[0][0] += av.x*bv.x; acc[0][1] += av.x*bv.y; acc[0][2] += av.x*bv.z; acc[0][3] += av.x*bv.w;
      acc[1][0] += av.y*bv.x; acc[1][1] += av.y*bv.y; acc[1][2] += av.y*bv.z; acc[1][3] += av.y*bv.w;
      acc[2][0] += av.z*bv.x; acc[2][1] += av.z*bv.y; acc[2][2] += av.z*bv.z; acc[2][3] += av.z*bv.w;
      acc[3][0] += av.w*bv.x; acc[3][1] += av.w*bv.y; acc[3][2] += av.w*bv.z; acc[3][3] += av.w*bv.w;
    }
    __syncthreads();
  }
  const float bnden = sqrtf(1.0f + 1e-5f);
  #pragma unroll
  for (int i = 0; i < 4; ++i) {
    const int r = bm + ty * 4 + i;
    if (r >= p.M) break;
    #pragma unroll
    for (int j = 0; j < 4; ++j) {
      const int c = bn + tx * 4 + j;
      if (c >= p.Nc) continue;
      float v = acc[i][j];
      if (p.bias) v += p.bias[c];
      if (p.bng)  v = v * (p.bng[c] / bnden) + p.bnb[c];
      if (Rb)     v += Rb[(size_t)r * p.Nc + c];
      if (p.act == 1)      v = fmaxf(v, 0.f);
      else if (p.act == 2) v = (v >= 0.f) ? v : 0.2f * v;
      Cb[(size_t)r * p.Nc + c] = v;
    }
  }
}

// ======================= fused flash attention over H=2047 pool
// y[r,:] = softmax_h(theta[r,:]·phi[h,:]) · gx[h,:]  per batch
// wg = 256 threads, 64 query rows; tiles of 32 pool cols.
__global__ __launch_bounds__(256) void attn_k(const float* __restrict__ theta,  // (B*N,128)
                                              const float* __restrict__ phiT,   // (B*H,128)
                                              const float* __restrict__ gxg,    // (B*H,128)
                                              float* __restrict__ y) {          // (B*N,128)
  __shared__ float thT[CO][68];      // [ch][row], padded for b128 reads
  __shared__ float ph[CO][34];       // [ch][col] transposed phi tile
  __shared__ float gxs[32][132];     // [h][ch] gx tile
  __shared__ float Ss[64][33];       // P tile
  const int b = blockIdx.y;
  const int row0 = blockIdx.x * 64;
  const int tid = threadIdx.x;
  const int tx = tid & 15, ty = tid >> 4;

  {
    const float* tb = theta + ((size_t)b * NN + row0) * CO;
    #pragma unroll
    for (int it = 0; it < 8; ++it) {
      int i = tid + it * 256;
      int r = i >> 5, c4 = (i & 31) << 2;
      const float4 v = *(const float4*)&tb[(size_t)r * CO + c4];
      thT[c4  ][r] = v.x; thT[c4+1][r] = v.y;
      thT[c4+2][r] = v.z; thT[c4+3][r] = v.w;
    }
  }

  float m[4], l[4], acc[4][8];
  #pragma unroll
  for (int i = 0; i < 4; ++i) {
    m[i] = -3.0e38f; l[i] = 0.f;
    #pragma unroll
    for (int j = 0; j < 8; ++j) acc[i][j] = 0.f;
  }

  const float* phb = phiT + (size_t)b * HH * CO;
  const float* gxb = gxg  + (size_t)b * HH * CO;

  for (int h0 = 0; h0 < HH; h0 += 32) {
    __syncthreads();
    #pragma unroll
    for (int it = 0; it < 4; ++it) {
      int i = tid + it * 256;
      int c = i >> 5, c4 = (i & 31) << 2;
      int hg = h0 + c;
      float4 v = make_float4(0.f,0.f,0.f,0.f), g = make_float4(0.f,0.f,0.f,0.f);
      if (hg < HH) {
        v = *(const float4*)&phb[(size_t)hg * CO + c4];
        g = *(const float4*)&gxb[(size_t)hg * CO + c4];
      }
      ph[c4  ][c] = v.x; ph[c4+1][c] = v.y;
      ph[c4+2][c] = v.z; ph[c4+3][c] = v.w;
      *(float4*)&gxs[c][c4] = g;
    }
    __syncthreads();

    // S = theta · phi^T  (rows ty*4..+3, cols tx*2..+1)
    float s[4][2] = {{0.f,0.f},{0.f,0.f},{0.f,0.f},{0.f,0.f}};
    #pragma unroll 8
    for (int ch = 0; ch < CO; ++ch) {
      const float4 av = *(const float4*)&thT[ch][ty*4];
      const float2 bv = *(const float2*)&ph[ch][tx*2];
      s[0][0] += av.x*bv.x; s[0][1] += av.x*bv.y;
      s[1][0] += av.y*bv.x; s[1][1] += av.y*bv.y;
      s[2][0] += av.z*bv.x; s[2][1] += av.z*bv.y;
      s[3][0] += av.w*bv.x; s[3][1] += av.w*bv.y;
    }
    if (h0 + 32 > HH) {          // mask padded pool cols (last tile)
      #pragma unroll
      for (int j = 0; j < 2; ++j)
        if (h0 + tx*2 + j >= HH) {
          s[0][j] = -3.0e38f; s[1][j] = -3.0e38f;
          s[2][j] = -3.0e38f; s[3][j] = -3.0e38f;
        }
    }

    // online softmax (row owned by 16 consecutive lanes)
    #pragma unroll
    for (int i = 0; i < 4; ++i) {
      float mx = fmaxf(s[i][0], s[i][1]);
      mx = fmaxf(mx, __shfl_xor(mx, 1));
      mx = fmaxf(mx, __shfl_xor(mx, 2));
      mx = fmaxf(mx, __shfl_xor(mx, 4));
      mx = fmaxf(mx, __shfl_xor(mx, 8));
      const float mn = fmaxf(m[i], mx);
      const float sc = __expf(m[i] - mn);
      m[i] = mn;
      const float e0 = __expf(s[i][0] - mn);
      const float e1 = __expf(s[i][1] - mn);
      float ps = e0 + e1;
      ps += __shfl_xor(ps, 1); ps += __shfl_xor(ps, 2);
      ps += __shfl_xor(ps, 4); ps += __shfl_xor(ps, 8);
      l[i] = l[i] * sc + ps;
      #pragma unroll
      for (int j = 0; j < 8; ++j) acc[i][j] *= sc;
      Ss[ty*4+i][tx*2  ] = e0;
      Ss[ty*4+i][tx*2+1] = e1;
    }
    __syncthreads();

    // acc += P · gx  (cols tx*4..+3 and 64+tx*4..+3)
    #pragma unroll 8
    for (int h = 0; h < 32; ++h) {
      const float p0 = Ss[ty*4  ][h];
      const float p1 = Ss[ty*4+1][h];
      const float p2 = Ss[ty*4+2][h];
      const float p3 = Ss[ty*4+3][h];
      const float4 g0 = *(const float4*)&gxs[h][tx*4];
      const float4 g1 = *(const float4*)&gxs[h][64 + tx*4];
      acc[0][0]+=p0*g0.x; acc[0][1]+=p0*g0.y; acc[0][2]+=p0*g0.z; acc[0][3]+=p0*g0.w;
      acc[0][4]+=p0*g1.x; acc[0][5]+=p0*g1.y; acc[0][6]+=p0*g1.z; acc[0][7]+=p0*g1.w;
      acc[1][0]+=p1*g0.x; acc[1][1]+=p1*g0.y; acc[1][2]+=p1*g0.z; acc[1][3]+=p1*g0.w;
      acc[1][4]+=p1*g1.x; acc[1][5]+=p1*g1.y; acc[1][6]+=p1*g1.z; acc[1][7]+=p1*g1.w;
      acc[2][0]+=p2*g0.x; acc[2][1]+=p2*g0.y; acc[2][2]+=p2*g0.z; acc[2][3]+=p2*g0.w;
      acc[2][4]+=p2*g1.x; acc[2][5]+=p2*g1.y; acc[2][6]+=p2*g1.z; acc[2][7]+=p2*g1.w;
      acc[3][0]+=p3*g0.x; acc[3][1]+=p3*g0.y; acc[3][2]+=p3*g0.z; acc[3][3]+=p3*g0.w;
      acc[3][4]+=p3*g1.x; acc[3][5]+=p3*g1.y; acc[3][6]+=p3*g1.z; acc[3][7]+=p3*g1.w;
    }
  }

  #pragma unroll
  for (int i = 0; i < 4; ++i) {
    const float inv = 1.0f / l[i];
    float* yr = y + ((size_t)b * NN + row0 + ty*4 + i) * CO;
    float4 o0 = make_float4(acc[i][0]*inv, acc[i][1]*inv, acc[i][2]*inv, acc[i][3]*inv);
    float4 o1 = make_float4(acc[i][4]*inv, acc[i][5]*inv, acc[i][6]*inv, acc[i][7]*inv);
    *(float4*)&yr[tx*4]    = o0;
    *(float4*)&yr[64+tx*4] = o1;
  }
}

// ======================= diff[b,n] = sum_k sum_c (flat[idx1]-xt)^2
__global__ __launch_bounds__(128) void diff_k(const float* __restrict__ xt,
                                              const int* __restrict__ idx1,
                                              float* __restrict__ diff) {
  __shared__ float r2[2];
  int bn = blockIdx.x;
  int c  = threadIdx.x;
  float xc = xt[(size_t)bn * CO + c];
  const int* id = idx1 + (size_t)bn * KNB;
  float acc = 0.f;
  #pragma unroll
  for (int k = 0; k < KNB; ++k) {
    int ix = id[k];
    float d = xt[(size_t)ix * CO + c] - xc;
    acc += d * d;
  }
  for (int o = 32; o; o >>= 1) acc += __shfl_xor(acc, o);
  if ((c & 63) == 0) r2[c >> 6] = acc;
  __syncthreads();
  if (c == 0) diff[bn] = r2[0] + r2[1];
}

// ======================= per-batch top-1638 bitonic + append inner
__global__ __launch_bounds__(1024) void topk_k(const float* __restrict__ diff,
                                               const int* __restrict__ inner,
                                               int* __restrict__ Hidx) {
  __shared__ uint64_t kv[NN];
  int b = blockIdx.x, tid = threadIdx.x;
  for (int i = tid; i < NN; i += 1024) {
    uint32_t bits = __float_as_uint(diff[(size_t)b * NN + i]);
    kv[i] = ((uint64_t)bits << 32) | (uint64_t)(NN - 1 - i);
  }
  __syncthreads();
  for (int k = 2; k <= NN; k <<= 1) {
    for (int j = k >> 1; j > 0; j >>= 1) {
      for (int t = tid; t < NN/2; t += 1024) {
        int i = ((t & ~(j - 1)) << 1) | (t & (j - 1));
        int q = i | j;
        uint64_t a = kv[i], c = kv[q];
        bool desc = ((i & k) == 0);
        bool sw = desc ? (a < c) : (a > c);
        if (sw) { kv[i] = c; kv[q] = a; }
      }
      __syncthreads();
    }
  }
  for (int t = tid; t < OUTER; t += 1024)
    Hidx[b * HH + t] = NN - 1 - (int)(kv[t] & 0xFFFFFFFFull);
  if (tid < INNER) Hidx[b * HH + OUTER + tid] = inner[tid];
}

// ======================= gather Hp rows
__global__ void hpgather_k(const float* __restrict__ xt,
                           const float* __restrict__ preds,
                           const int* __restrict__ Hidx,
                           float* __restrict__ HpA) {
  int b = blockIdx.y, h = blockIdx.x;
  int src = Hidx[b * HH + h];
  size_t srow = (size_t)b * NN + src;
  size_t drow = (size_t)b * HH + h;
  int t = threadIdx.x;
  if (t < CO)            HpA[drow * 149 + t] = xt[srow * CO + t];
  else if (t < CO + CLS) HpA[drow * 149 + t] = preds[srow * CLS + (t - CO)];
}

// ======================= log_softmax over 21 logits
__global__ __launch_bounds__(256) void logsm_k(const float* __restrict__ logits,
                                               float* __restrict__ out) {
  int r = blockIdx.x * 256 + threadIdx.x;
  if (r >= BB * NN) return;
  const float* l = logits + (size_t)r * CLS;
  float*       o = out    + (size_t)r * CLS;
  float m = l[0];
  #pragma unroll
  for (int i = 1; i < CLS; ++i) m = fmaxf(m, l[i]);
  float s = 0.f;
  #pragma unroll
  for (int i = 0; i < CLS; ++i) s += expf(l[i] - m);
  float lse = m + logf(s);
  #pragma unroll
  for (int i = 0; i < CLS; ++i) o[i] = l[i] - lse;
}

static inline dim3 ggrid(int M, int Nc) { return dim3((Nc + 63) / 64, (M + 63) / 64); }

} // anonymous namespace

// ===========================================================================
extern "C" void kernel_launch(void* const* d_in, const int* in_sizes, int n_in,
                              void* d_out, int out_size, void* d_ws, size_t ws_size,
                              hipStream_t stream) {
  const float* xyz1    = (const float*)d_in[0];
  const float* xyz2    = (const float*)d_in[1];
  const float* points1 = (const float*)d_in[2];
  const float* points2 = (const float*)d_in[3];
  const float* lastpred= (const float*)d_in[5];
  const float* w_mlp0  = (const float*)d_in[6];
  const float* b_mlp0  = (const float*)d_in[7];
  const float* g_bn0   = (const float*)d_in[8];
  const float* be_bn0  = (const float*)d_in[9];
  const float* w_mlp1  = (const float*)d_in[10];
  const float* b_mlp1  = (const float*)d_in[11];
  const float* g_bn1   = (const float*)d_in[12];
  const float* be_bn1  = (const float*)d_in[13];
  const float* w_h     = (const float*)d_in[14];
  const float* g_hbn   = (const float*)d_in[15];
  const float* be_hbn  = (const float*)d_in[16];
  const float* w_outm  = (const float*)d_in[17];
  const float* g_obn   = (const float*)d_in[18];
  const float* be_obn  = (const float*)d_in[19];
  const float* w_g     = (const float*)d_in[20];
  const float* b_g     = (const float*)d_in[21];
  const float* w_theta = (const float*)d_in[22];
  const float* b_theta = (const float*)d_in[23];
  const float* w_phi   = (const float*)d_in[24];
  const float* b_phi   = (const float*)d_in[25];
  const float* w_W     = (const float*)d_in[26];
  const float* b_W     = (const float*)d_in[27];
  const float* g_Wbn   = (const float*)d_in[28];
  const float* be_Wbn  = (const float*)d_in[29];
  const float* w5      = (const float*)d_in[30];
  const float* b5      = (const float*)d_in[31];
  const float* g_bn5   = (const float*)d_in[32];
  const float* be_bn5  = (const float*)d_in[33];
  const float* w6      = (const float*)d_in[34];
  const float* b6      = (const float*)d_in[35];
  const int*   idx_1   = (const int*)d_in[36];

  float* out0 = (float*)d_out;
  float* out1 = out0 + (size_t)BB * CO * NN;

  char* base = (char*)d_ws;
  size_t off = 0;
  auto alloc = [&](size_t bytes) -> char* {
    char* p = base + off;
    off += (bytes + 255) & ~(size_t)255;
    return p;
  };
  int*   inner  = (int*)  alloc((size_t)INNER * 4);
  int*   idx3   = (int*)  alloc((size_t)BB * NN * 3 * 4);
  float* w3     = (float*)alloc((size_t)BB * NN * 3 * 4);
  float* diff   = (float*)alloc((size_t)BB * NN * 4);
  int*   Hidx   = (int*)  alloc((size_t)BB * HH * 4);
  float* preds  = (float*)alloc((size_t)BB * NN * CLS * 4);
  float* HpA    = (float*)alloc((size_t)BB * HH * 149 * 4);
  float* Hp2    = (float*)alloc((size_t)BB * HH * CO * 4);
  float* gx     = (float*)alloc((size_t)BB * HH * CO * 4);
  float* phiT   = (float*)alloc((size_t)BB * HH * CO * 4);
  float* xt     = (float*)alloc((size_t)BB * NN * CO * 4);
  char*  RI     =         alloc((size_t)BB * NN * 256 * 4);
  char*  RX     =         alloc((size_t)BB * NN * 256 * 4);
  float* p2t    = (float*)alloc((size_t)BB * SS * 256 * 4);
  if (off > ws_size) return;

  float* interp = (float*)RI;
  float* theta  = (float*)RI;
  float* yattn  = (float*)(RI + (size_t)BB * NN * CO * 4);
  float* x2     = (float*)RX;
  float* zbuf   = (float*)RX;
  float* h5     = (float*)RX;
  float* npo    = (float*)(RX + (size_t)BB * NN * CO * 4);
  float* logits = preds;

  // 1. inner indices
  inner_idx_k<<<1, 512, 0, stream>>>(inner);

  // 2. transpose points2 (B,256,S) -> (B,S,256)
  transpose_k<<<dim3(SS/32, 256/32, BB), dim3(32, 8), 0, stream>>>(
      points2, p2t, 256, SS, (long long)256 * SS, (long long)SS * 256);

  // 3. 3-NN
  knn_k<<<dim3(NN/256, BB), 256, 0, stream>>>(xyz1, xyz2, idx3, w3);

  // 4. interpolate
  interp_k<<<dim3(NN, BB), 256, 0, stream>>>(p2t, lastpred, idx3, w3, interp, preds);

  // 5. mlp0 (z-batched over B)
  {
    GemmP p{};
    p.A = points1; p.A1T = 1; p.lda1 = NN; p.K1 = 256;
    p.A2 = interp;
    p.W = w_mlp0;
    p.bias = b_mlp0; p.bng = g_bn0; p.bnb = be_bn0;
    p.C = x2;
    p.M = NN; p.Nc = 256; p.K = 512; p.act = 1;
    p.zA = (long long)256 * NN; p.zA2 = (long long)NN * 256; p.zC = (long long)NN * 256;
    gemm_k<<<dim3(4, 128, BB), 256, 0, stream>>>(p);
  }

  // 6. mlp1 -> xt
  {
    GemmP p{};
    p.A = x2; p.K1 = 256; p.W = w_mlp1;
    p.bias = b_mlp1; p.bng = g_bn1; p.bnb = be_bn1;
    p.C = xt; p.M = BB * NN; p.Nc = CO; p.K = 256; p.act = 1;
    gemm_k<<<ggrid(BB * NN, CO), 256, 0, stream>>>(p);
  }

  // 7. KNN feature variance score
  diff_k<<<BB * NN, 128, 0, stream>>>(xt, idx_1, diff);

  // 8. per-batch top-1638 (+ inner)
  topk_k<<<BB, 1024, 0, stream>>>(diff, inner, Hidx);

  // 9. gather Hp rows
  hpgather_k<<<dim3(HH, BB), 192, 0, stream>>>(xt, preds, Hidx, HpA);

  // 10. conv_h
  {
    GemmP p{};
    p.A = HpA; p.K1 = 149; p.W = w_h;
    p.bng = g_hbn; p.bnb = be_hbn;
    p.C = Hp2; p.M = BB * HH; p.Nc = CO; p.K = 149; p.act = 2;
    gemm_k<<<ggrid(BB * HH, CO), 256, 0, stream>>>(p);
  }
  // 11. g_x
  {
    GemmP p{};
    p.A = Hp2; p.K1 = CO; p.W = w_g; p.bias = b_g;
    p.C = gx; p.M = BB * HH; p.Nc = CO; p.K = CO; p.act = 0;
    gemm_k<<<ggrid(BB * HH, CO), 256, 0, stream>>>(p);
  }
  // 12. phi
  {
    GemmP p{};
    p.A = Hp2; p.K1 = CO; p.W = w_phi; p.bias = b_phi;
    p.C = phiT; p.M = BB * HH; p.Nc = CO; p.K = CO; p.act = 0;
    gemm_k<<<ggrid(BB * HH, CO), 256, 0, stream>>>(p);
  }
  // 13. theta
  {
    GemmP p{};
    p.A = xt; p.K1 = CO; p.W = w_theta; p.bias = b_theta;
    p.C = theta; p.M = BB * NN; p.Nc = CO; p.K = CO; p.act = 0;
    gemm_k<<<ggrid(BB * NN, CO), 256, 0, stream>>>(p);
  }

  // 14. fused flash attention: y = softmax(theta·phi^T)·g_x
  attn_k<<<dim3(NN/64, BB), 256, 0, stream>>>(theta, phiT, gx, yattn);

  // 15. z = bn_W(W_W*y + b_W) + x
  {
    GemmP p{};
    p.A = yattn; p.K1 = CO; p.W = w_W; p.bias = b_W;
    p.bng = g_Wbn; p.bnb = be_Wbn; p.res = xt;
    p.C = zbuf; p.M = BB * NN; p.Nc = CO; p.K = CO; p.act = 0;
    gemm_k<<<ggrid(BB * NN, CO), 256, 0, stream>>>(p);
  }
  // 16. new_points_out
  {
    GemmP p{};
    p.A = zbuf; p.K1 = CO; p.W = w_outm;
    p.bng = g_obn; p.bnb = be_obn;
    p.C = npo; p.M = BB * NN; p.Nc = CO; p.K = CO; p.act = 2;
    gemm_k<<<ggrid(BB * NN, CO), 256, 0, stream>>>(p);
  }
  // 17. transpose npo -> out0
  transpose_k<<<dim3(CO/32, NN/32, BB), dim3(32, 8), 0, stream>>>(
      npo, out0, NN, CO, (long long)NN * CO, (long long)CO * NN);

  // 18. h5
  {
    GemmP p{};
    p.A = npo; p.K1 = CO; p.W = w5; p.bias = b5;
    p.bng = g_bn5; p.bnb = be_bn5;
    p.C = h5; p.M = BB * NN; p.Nc = 32; p.K = CO; p.act = 1;
    gemm_k<<<ggrid(BB * NN, 32), 256, 0, stream>>>(p);
  }
  // 19. logits
  {
    GemmP p{};
    p.A = h5; p.K1 = 32; p.W = w6; p.bias = b6;
    p.C = logits; p.M = BB * NN; p.Nc = CLS; p.K = 32; p.act = 0;
    gemm_k<<<ggrid(BB * NN, CLS), 256, 0, stream>>>(p);
  }
  // 20. log_softmax
  logsm_k<<<(BB * NN + 255) / 256, 256, 0, stream>>>(logits, out1);
}

// Round 3
// 1078.267 us; speedup vs baseline: 6.3305x; 1.4375x over previous
//
#include <hip/hip_runtime.h>
#include <stdint.h>
#include <math.h>

// ---------------------------------------------------------------------------
// IAF_PointNetFeaturePropagation: f32 pipeline + bf16-MFMA flash attention.
// B=4, N=8192, S=2048, K=20, D1=D2=256, CO=128, CLS=21, H=1638+409=2047
// ---------------------------------------------------------------------------

namespace {

constexpr int BB   = 4;
constexpr int NN   = 8192;
constexpr int SS   = 2048;
constexpr int KNB  = 20;
constexpr int CO   = 128;
constexpr int CLS  = 21;
constexpr int HH   = 2047;
constexpr int OUTER= 1638;
constexpr int INNER= 409;

typedef unsigned short u16;
typedef short bf8 __attribute__((ext_vector_type(8)));   // 8 bf16 in 4 VGPRs
typedef float f4  __attribute__((ext_vector_type(4)));   // MFMA accumulator

__device__ inline u16 f2bf(float f) {                    // round-nearest-even
  uint32_t x = __float_as_uint(f);
  return (u16)((x + 0x7FFFu + ((x >> 16) & 1u)) >> 16);
}

// ======================= numpy default_rng(0).choice(8192,409,replace=False)
__global__ __launch_bounds__(512) void inner_idx_k(int* __restrict__ out) {
  __shared__ uint64_t hs[512];
  hs[threadIdx.x] = ~0ull;
  __syncthreads();
  if (threadIdx.x != 0) return;

  uint32_t pool[4];
  uint32_t hc = 0x43b0d7e5u;
  auto hashmix = [&hc](uint32_t v) -> uint32_t {
    v ^= hc; hc *= 0x931e8875u; v *= hc; v ^= v >> 16; return v;
  };
  auto mixf = [](uint32_t x, uint32_t y) -> uint32_t {
    uint32_t r = x * 0xca01f9ddu; r ^= y * 0x4973f715u; r ^= r >> 16; return r;
  };
  pool[0] = hashmix(0u); pool[1] = hashmix(0u);
  pool[2] = hashmix(0u); pool[3] = hashmix(0u);
  for (int s = 0; s < 4; ++s)
    for (int d = 0; d < 4; ++d)
      if (s != d) pool[d] = mixf(pool[d], hashmix(pool[s]));

  uint32_t st32[8];
  uint32_t hb = 0x8b51f9ddu;
  for (int i = 0; i < 8; ++i) {
    uint32_t dv = pool[i & 3];
    dv ^= hb; hb *= 0x58f38dedu; dv *= hb; dv ^= dv >> 16;
    st32[i] = dv;
  }
  uint64_t s64[4];
  for (int i = 0; i < 4; ++i)
    s64[i] = (uint64_t)st32[2*i] | ((uint64_t)st32[2*i+1] << 32);

  typedef unsigned __int128 u128;
  const u128 MUL = ((u128)2549297995355413924ull << 64) | (u128)4865540595714422341ull;
  u128 inc   = (((((u128)s64[2]) << 64) | (u128)s64[3]) << 1) | 1;
  u128 state = inc;
  state += (((u128)s64[0]) << 64) | (u128)s64[1];
  state = state * MUL + inc;

  bool has32 = false; uint32_t buf32 = 0;
  auto next32 = [&]() -> uint32_t {
    if (has32) { has32 = false; return buf32; }
    state = state * MUL + inc;
    uint64_t hi = (uint64_t)(state >> 64), lo = (uint64_t)state;
    uint64_t x = hi ^ lo;
    unsigned rot = (unsigned)(state >> 122);
    uint64_t v = (x >> rot) | (x << ((64u - rot) & 63u));
    has32 = true; buf32 = (uint32_t)(v >> 32);
    return (uint32_t)v;
  };

  for (int j = NN - INNER; j < NN; ++j) {
    uint32_t rng = (uint32_t)j, rng_excl = rng + 1u;
    uint64_t m = (uint64_t)next32() * (uint64_t)rng_excl;
    uint32_t leftover = (uint32_t)m;
    if (leftover < rng_excl) {
      uint32_t threshold = (0xFFFFFFFFu - rng) % rng_excl;
      while (leftover < threshold) {
        m = (uint64_t)next32() * (uint64_t)rng_excl;
        leftover = (uint32_t)m;
      }
    }
    uint64_t val = m >> 32;
    uint32_t loc = (uint32_t)val & 511u;
    while (hs[loc] != ~0ull && hs[loc] != val) loc = (loc + 1u) & 511u;
    uint64_t chosen;
    if (hs[loc] == ~0ull) { hs[loc] = val; chosen = val; }
    else                  { hs[loc] = (uint64_t)j; chosen = (uint64_t)j; }
    out[j - (NN - INNER)] = (int)chosen;
  }
}

// ======================= generic 32x32-tiled transpose
__global__ void transpose_k(const float* __restrict__ in, float* __restrict__ out,
                            int R, int Cc, long long inB, long long outB) {
  __shared__ float t[32][33];
  const float* ib = in  + (long long)blockIdx.z * inB;
  float*       ob = out + (long long)blockIdx.z * outB;
  int c0 = blockIdx.x * 32, r0 = blockIdx.y * 32;
  int tx = threadIdx.x, ty = threadIdx.y;
  for (int i = 0; i < 32; i += 8) {
    int r = r0 + ty + i, c = c0 + tx;
    if (r < R && c < Cc) t[ty + i][tx] = ib[(size_t)r * Cc + c];
  }
  __syncthreads();
  for (int i = 0; i < 32; i += 8) {
    int c = c0 + ty + i, r = r0 + tx;
    if (r < R && c < Cc) ob[(size_t)c * R + r] = t[tx][ty + i];
  }
}

// ======================= 3-NN over S=2048
__global__ __launch_bounds__(256) void knn_k(const float* __restrict__ xyz1,
                                             const float* __restrict__ xyz2,
                                             int* __restrict__ idx3,
                                             float* __restrict__ w3) {
  __shared__ float X[SS], Y[SS], Z[SS], SSQ[SS];
  int b = blockIdx.y;
  const float* x2 = xyz2 + (size_t)b * SS * 3;
  for (int i = threadIdx.x; i < SS; i += 256) {
    float x = x2[i*3], y = x2[i*3+1], z = x2[i*3+2];
    X[i] = x; Y[i] = y; Z[i] = z; SSQ[i] = x*x + y*y + z*z;
  }
  __syncthreads();
  int n = blockIdx.x * 256 + threadIdx.x;
  const float* p = xyz1 + ((size_t)b * NN + n) * 3;
  float px = p[0], py = p[1], pz = p[2];
  float ss1 = px*px + py*py + pz*pz;
  float d0 = 3.4e38f, d1 = 3.4e38f, d2 = 3.4e38f;
  int   i0 = 0, i1 = 0, i2 = 0;
  for (int s = 0; s < SS; ++s) {
    float d = (ss1 + SSQ[s]) - 2.0f * (px*X[s] + py*Y[s] + pz*Z[s]);
    if (d < d2) {
      if (d < d1) {
        d2 = d1; i2 = i1;
        if (d < d0) { d1 = d0; i1 = i0; d0 = d; i0 = s; }
        else        { d1 = d;  i1 = s; }
      } else { d2 = d; i2 = s; }
    }
  }
  d0 = fmaxf(d0, 1e-10f); d1 = fmaxf(d1, 1e-10f); d2 = fmaxf(d2, 1e-10f);
  float w0 = 1.f/d0, w1 = 1.f/d1, w2 = 1.f/d2;
  float ws = w0 + w1 + w2;
  size_t o = (size_t)b * NN + n;
  idx3[o*3] = i0; idx3[o*3+1] = i1; idx3[o*3+2] = i2;
  w3[o*3] = w0/ws; w3[o*3+1] = w1/ws; w3[o*3+2] = w2/ws;
}

// ======================= interpolation gather
__global__ __launch_bounds__(256) void interp_k(const float* __restrict__ p2t,
                                                const float* __restrict__ lastpred,
                                                const int* __restrict__ idx3,
                                                const float* __restrict__ w3,
                                                float* __restrict__ interp,
                                                float* __restrict__ preds) {
  int b = blockIdx.y, n = blockIdx.x;
  size_t o = (size_t)b * NN + n;
  int i0 = idx3[o*3], i1 = idx3[o*3+1], i2 = idx3[o*3+2];
  float w0 = w3[o*3], w1 = w3[o*3+1], w2 = w3[o*3+2];
  const float* pb = p2t + (size_t)b * SS * 256;
  int c = threadIdx.x;
  interp[o*256 + c] = w0 * pb[(size_t)i0*256 + c]
                    + w1 * pb[(size_t)i1*256 + c]
                    + w2 * pb[(size_t)i2*256 + c];
  if (c < CLS) {
    const float* lp = lastpred + (size_t)b * SS * CLS;
    preds[o*CLS + c] = w0 * lp[i0*CLS + c] + w1 * lp[i1*CLS + c] + w2 * lp[i2*CLS + c];
  }
}

// ======================= generic f32 GEMM with fused epilogue (z-batched)
// omode: 0 = f32 row-major; 1 = bf16 row-major; 2 = bf16 transposed per-batch
//        (rows split as b = r/HH, rr = r%HH; write [(b*Nc + c)*2048 + rr])
struct GemmP {
  const float* A;  const float* A2; const float* W;
  const float* bias; const float* bng; const float* bnb; const float* res;
  float* C;
  int M, Nc, K, K1, lda1, A1T, WT, act, omode;
  long long zA, zA2, zC;
};

__global__ __launch_bounds__(256) void gemm_k(GemmP p) {
  __shared__ float As[16][68];
  __shared__ float Ws[16][68];
  const float* Ab  = p.A  + (size_t)blockIdx.z * p.zA;
  const float* A2b = p.A2 + (size_t)blockIdx.z * p.zA2;
  float*       Cb  = p.C  + (size_t)blockIdx.z * p.zC;
  const float* Rb  = p.res ? p.res + (size_t)blockIdx.z * p.zC : nullptr;
  const int bm = blockIdx.y * 64, bn = blockIdx.x * 64;
  const int tid = threadIdx.x;
  const int tx = tid & 15, ty = tid >> 4;
  float acc[4][4] = {{0.f,0.f,0.f,0.f},{0.f,0.f,0.f,0.f},{0.f,0.f,0.f,0.f},{0.f,0.f,0.f,0.f}};
  const int K2 = p.K - p.K1;
  for (int k0 = 0; k0 < p.K; k0 += 16) {
    if (p.A1T && k0 < p.K1) {
      const int mm = tid & 63, kb = tid >> 6;
      #pragma unroll
      for (int kk = kb; kk < 16; kk += 4) {
        const int gm = bm + mm, gk = k0 + kk;
        As[kk][mm] = (gm < p.M && gk < p.K1) ? Ab[(size_t)gk * p.lda1 + gm] : 0.f;
      }
    } else {
      const int kk = tid & 15, mb = tid >> 4;
      #pragma unroll
      for (int mm = mb; mm < 64; mm += 16) {
        const int gm = bm + mm, gk = k0 + kk;
        float v = 0.f;
        if (gm < p.M && gk < p.K)
          v = (gk < p.K1) ? Ab[(size_t)gm * p.K1 + gk]
                          : A2b[(size_t)gm * K2 + (gk - p.K1)];
        As[kk][mm] = v;
      }
    }
    if (p.WT) {
      const int nn = tid & 63, kb = tid >> 6;
      #pragma unroll
      for (int kk = kb; kk < 16; kk += 4) {
        const int gn = bn + nn, gk = k0 + kk;
        Ws[kk][nn] = (gn < p.Nc && gk < p.K) ? p.W[(size_t)gk * p.Nc + gn] : 0.f;
      }
    } else {
      const int kk = tid & 15, nb = tid >> 4;
      #pragma unroll
      for (int nn = nb; nn < 64; nn += 16) {
        const int gn = bn + nn, gk = k0 + kk;
        Ws[kk][nn] = (gn < p.Nc && gk < p.K) ? p.W[(size_t)gn * p.K + gk] : 0.f;
      }
    }
    __syncthreads();
    #pragma unroll
    for (int kk = 0; kk < 16; ++kk) {
      const float4 av = *(const float4*)&As[kk][ty * 4];
      const float4 bv = *(const float4*)&Ws[kk][tx * 4];
      acc[0][0] += av.x*bv.x; acc[0][1] += av.x*bv.y; acc[0][2] += av.x*bv.z; acc[0][3] += av.x*bv.w;
      acc[1][0] += av.y*bv.x; acc[1][1] += av.y*bv.y; acc[1][2] += av.y*bv.z; acc[1][3] += av.y*bv.w;
      acc[2][0] += av.z*bv.x; acc[2][1] += av.z*bv.y; acc[2][2] += av.z*bv.z; acc[2][3] += av.z*bv.w;
      acc[3][0] += av.w*bv.x; acc[3][1] += av.w*bv.y; acc[3][2] += av.w*bv.z; acc[3][3] += av.w*bv.w;
    }
    __syncthreads();
  }
  const float bnden = sqrtf(1.0f + 1e-5f);
  #pragma unroll
  for (int i = 0; i < 4; ++i) {
    const int r = bm + ty * 4 + i;
    if (r >= p.M) break;
    #pragma unroll
    for (int j = 0; j < 4; ++j) {
      const int c = bn + tx * 4 + j;
      if (c >= p.Nc) continue;
      float v = acc[i][j];
      if (p.bias) v += p.bias[c];
      if (p.bng)  v = v * (p.bng[c] / bnden) + p.bnb[c];
      if (Rb)     v += Rb[(size_t)r * p.Nc + c];
      if (p.act == 1)      v = fmaxf(v, 0.f);
      else if (p.act == 2) v = (v >= 0.f) ? v : 0.2f * v;
      if (p.omode == 0) {
        Cb[(size_t)r * p.Nc + c] = v;
      } else if (p.omode == 1) {
        ((u16*)Cb)[(size_t)r * p.Nc + c] = f2bf(v);
      } else {
        const int bb = r / HH, rr = r - bb * HH;
        ((u16*)Cb)[((size_t)(bb * p.Nc + c)) * 2048 + rr] = f2bf(v);
      }
    }
  }
}

// ======================= bf16-MFMA flash attention over the 2047-pool
// Block: 256 thr = 4 waves, 64 query rows (16/wave). KV tiles of 64.
// S: mfma(theta_frag, phi_frag); P via per-wave LDS; PV: mfma(P_frag, V_frag).
__global__ __launch_bounds__(256) void attn_mfma_k(
    const u16* __restrict__ thetab,   // (B*N,128) bf16 row-major
    const u16* __restrict__ phib,     // (B*H,128) bf16 row-major
    const u16* __restrict__ gxT,      // (B,128,2048) bf16 (V transposed, col 2047 junk)
    float* __restrict__ y)            // (B*N,128) f32
{
  __shared__ u16 Kt[64 * 128];   // phi tile, 16B-chunk XOR swizzled (chunk^=(row&7))
  __shared__ u16 Vt[128 * 64];   // gxT tile, chunk^=(row&7)
  __shared__ u16 Pt[64 * 72];    // P tile, row stride 72 bf16 (144B)
  const int b    = blockIdx.y;
  const int row0 = blockIdx.x * 64;
  const int tid  = threadIdx.x;
  const int wave = tid >> 6;
  const int lane = tid & 63;
  const int l15  = lane & 15, l4 = lane >> 4;

  // Q fragments in registers: aq[ks] covers k = ks*32 + l4*8 .. +7
  bf8 aq[4];
  {
    const u16* tq = thetab + ((size_t)(b * NN + row0 + wave * 16 + l15)) * 128;
    #pragma unroll
    for (int ks = 0; ks < 4; ++ks)
      aq[ks] = *(const bf8*)(tq + ks * 32 + l4 * 8);
  }

  f4 acc[8];
  #pragma unroll
  for (int i = 0; i < 8; ++i) acc[i] = (f4){0.f, 0.f, 0.f, 0.f};
  float mrow[4] = {-3e38f, -3e38f, -3e38f, -3e38f};
  float lrow[4] = {0.f, 0.f, 0.f, 0.f};

  const u16* phbase = phib + (size_t)b * HH * 128;
  const u16* gxbase = gxT  + (size_t)b * 128 * 2048;

  for (int h0 = 0; h0 < 2048; h0 += 64) {
    __syncthreads();
    // stage Kt: 64 rows x 16 chunks of 16B
    #pragma unroll
    for (int it = 0; it < 4; ++it) {
      int id = it * 256 + tid;
      int r = id >> 4, ch = id & 15;
      int gp = h0 + r;
      bf8 vv = {0,0,0,0,0,0,0,0};
      if (gp < HH) vv = *(const bf8*)(phbase + (size_t)gp * 128 + ch * 8);
      *(bf8*)&Kt[r * 128 + ((ch ^ (r & 7)) << 3)] = vv;
    }
    // stage Vt: 128 rows x 8 chunks of 16B
    #pragma unroll
    for (int it = 0; it < 4; ++it) {
      int id = it * 256 + tid;
      int c = id >> 3, ch = id & 7;
      bf8 vv = *(const bf8*)(gxbase + (size_t)c * 2048 + h0 + ch * 8);
      *(bf8*)&Vt[c * 64 + ((ch ^ (c & 7)) << 3)] = vv;
    }
    __syncthreads();

    // ---- S = theta · phi^T : 4 col-tiles x 4 k-steps
    f4 sacc[4];
    #pragma unroll
    for (int t = 0; t < 4; ++t) sacc[t] = (f4){0.f, 0.f, 0.f, 0.f};
    #pragma unroll
    for (int ks = 0; ks < 4; ++ks) {
      #pragma unroll
      for (int t = 0; t < 4; ++t) {
        const int pr = t * 16 + l15;                 // pool row in tile
        const int ch = (ks * 4 + l4) ^ (pr & 7);
        bf8 bk = *(const bf8*)&Kt[pr * 128 + ch * 8];
        sacc[t] = __builtin_amdgcn_mfma_f32_16x16x32_bf16(aq[ks], bk, sacc[t], 0, 0, 0);
      }
    }
    if (h0 + 64 > HH) {                              // mask pad col 2047
      #pragma unroll
      for (int t = 0; t < 4; ++t)
        if (h0 + t * 16 + l15 >= HH)
          sacc[t] = (f4){-3e38f, -3e38f, -3e38f, -3e38f};
    }

    // ---- online softmax: row = wave*16 + l4*4 + r, owned by 16 lanes (l15)
    float e[4][4];
    #pragma unroll
    for (int r = 0; r < 4; ++r) {
      float tm = fmaxf(fmaxf(sacc[0][r], sacc[1][r]), fmaxf(sacc[2][r], sacc[3][r]));
      tm = fmaxf(tm, __shfl_xor(tm, 1));
      tm = fmaxf(tm, __shfl_xor(tm, 2));
      tm = fmaxf(tm, __shfl_xor(tm, 4));
      tm = fmaxf(tm, __shfl_xor(tm, 8));
      const float mn = fmaxf(mrow[r], tm);
      const float sc = __expf(mrow[r] - mn);
      mrow[r] = mn;
      float ps = 0.f;
      #pragma unroll
      for (int t = 0; t < 4; ++t) {
        float ev = __expf(sacc[t][r] - mn);
        e[t][r] = ev; ps += ev;
      }
      ps += __shfl_xor(ps, 1); ps += __shfl_xor(ps, 2);
      ps += __shfl_xor(ps, 4); ps += __shfl_xor(ps, 8);
      lrow[r] = lrow[r] * sc + ps;
      #pragma unroll
      for (int ct = 0; ct < 8; ++ct) acc[ct][r] *= sc;
    }
    // write P (wave-local rows; only this wave reads them back)
    #pragma unroll
    for (int r = 0; r < 4; ++r) {
      const int prow = wave * 16 + l4 * 4 + r;
      #pragma unroll
      for (int t = 0; t < 4; ++t)
        Pt[prow * 72 + t * 16 + l15] = f2bf(e[t][r]);
    }

    // ---- acc += P · V : 2 k-steps x 8 channel-tiles
    #pragma unroll
    for (int ks = 0; ks < 2; ++ks) {
      bf8 pa = *(const bf8*)&Pt[(wave * 16 + l15) * 72 + (ks * 4 + l4) * 8];
      #pragma unroll
      for (int ct = 0; ct < 8; ++ct) {
        const int c  = ct * 16 + l15;                // output channel
        const int ch = (ks * 4 + l4) ^ (c & 7);
        bf8 bv = *(const bf8*)&Vt[c * 64 + ch * 8];
        acc[ct] = __builtin_amdgcn_mfma_f32_16x16x32_bf16(pa, bv, acc[ct], 0, 0, 0);
      }
    }
  }

  // epilogue: y = acc / l
  float* yo = y + ((size_t)(b * NN + row0 + wave * 16 + l4 * 4)) * 128;
  #pragma unroll
  for (int r = 0; r < 4; ++r) {
    const float inv = 1.0f / lrow[r];
    #pragma unroll
    for (int ct = 0; ct < 8; ++ct)
      yo[(size_t)r * 128 + ct * 16 + l15] = acc[ct][r] * inv;
  }
}

// ======================= diff[b,n] = sum_k sum_c (flat[idx1]-xt)^2
__global__ __launch_bounds__(128) void diff_k(const float* __restrict__ xt,
                                              const int* __restrict__ idx1,
                                              float* __restrict__ diff) {
  __shared__ float r2[2];
  int bn = blockIdx.x;
  int c  = threadIdx.x;
  float xc = xt[(size_t)bn * CO + c];
  const int* id = idx1 + (size_t)bn * KNB;
  float acc = 0.f;
  #pragma unroll
  for (int k = 0; k < KNB; ++k) {
    int ix = id[k];
    float d = xt[(size_t)ix * CO + c] - xc;
    acc += d * d;
  }
  for (int o = 32; o; o >>= 1) acc += __shfl_xor(acc, o);
  if ((c & 63) == 0) r2[c >> 6] = acc;
  __syncthreads();
  if (c == 0) diff[bn] = r2[0] + r2[1];
}

// ======================= per-batch top-1638 bitonic + append inner
__global__ __launch_bounds__(1024) void topk_k(const float* __restrict__ diff,
                                               const int* __restrict__ inner,
                                               int* __restrict__ Hidx) {
  __shared__ uint64_t kv[NN];
  int b = blockIdx.x, tid = threadIdx.x;
  for (int i = tid; i < NN; i += 1024) {
    uint32_t bits = __float_as_uint(diff[(size_t)b * NN + i]);
    kv[i] = ((uint64_t)bits << 32) | (uint64_t)(NN - 1 - i);
  }
  __syncthreads();
  for (int k = 2; k <= NN; k <<= 1) {
    for (int j = k >> 1; j > 0; j >>= 1) {
      for (int t = tid; t < NN/2; t += 1024) {
        int i = ((t & ~(j - 1)) << 1) | (t & (j - 1));
        int q = i | j;
        uint64_t a = kv[i], c = kv[q];
        bool desc = ((i & k) == 0);
        bool sw = desc ? (a < c) : (a > c);
        if (sw) { kv[i] = c; kv[q] = a; }
      }
      __syncthreads();
    }
  }
  for (int t = tid; t < OUTER; t += 1024)
    Hidx[b * HH + t] = NN - 1 - (int)(kv[t] & 0xFFFFFFFFull);
  if (tid < INNER) Hidx[b * HH + OUTER + tid] = inner[tid];
}

// ======================= gather Hp rows
__global__ void hpgather_k(const float* __restrict__ xt,
                           const float* __restrict__ preds,
                           const int* __restrict__ Hidx,
                           float* __restrict__ HpA) {
  int b = blockIdx.y, h = blockIdx.x;
  int src = Hidx[b * HH + h];
  size_t srow = (size_t)b * NN + src;
  size_t drow = (size_t)b * HH + h;
  int t = threadIdx.x;
  if (t < CO)            HpA[drow * 149 + t] = xt[srow * CO + t];
  else if (t < CO + CLS) HpA[drow * 149 + t] = preds[srow * CLS + (t - CO)];
}

// ======================= log_softmax over 21 logits
__global__ __launch_bounds__(256) void logsm_k(const float* __restrict__ logits,
                                               float* __restrict__ out) {
  int r = blockIdx.x * 256 + threadIdx.x;
  if (r >= BB * NN) return;
  const float* l = logits + (size_t)r * CLS;
  float*       o = out    + (size_t)r * CLS;
  float m = l[0];
  #pragma unroll
  for (int i = 1; i < CLS; ++i) m = fmaxf(m, l[i]);
  float s = 0.f;
  #pragma unroll
  for (int i = 0; i < CLS; ++i) s += expf(l[i] - m);
  float lse = m + logf(s);
  #pragma unroll
  for (int i = 0; i < CLS; ++i) o[i] = l[i] - lse;
}

static inline dim3 ggrid(int M, int Nc) { return dim3((Nc + 63) / 64, (M + 63) / 64); }

} // anonymous namespace

// ===========================================================================
extern "C" void kernel_launch(void* const* d_in, const int* in_sizes, int n_in,
                              void* d_out, int out_size, void* d_ws, size_t ws_size,
                              hipStream_t stream) {
  const float* xyz1    = (const float*)d_in[0];
  const float* xyz2    = (const float*)d_in[1];
  const float* points1 = (const float*)d_in[2];
  const float* points2 = (const float*)d_in[3];
  const float* lastpred= (const float*)d_in[5];
  const float* w_mlp0  = (const float*)d_in[6];
  const float* b_mlp0  = (const float*)d_in[7];
  const float* g_bn0   = (const float*)d_in[8];
  const float* be_bn0  = (const float*)d_in[9];
  const float* w_mlp1  = (const float*)d_in[10];
  const float* b_mlp1  = (const float*)d_in[11];
  const float* g_bn1   = (const float*)d_in[12];
  const float* be_bn1  = (const float*)d_in[13];
  const float* w_h     = (const float*)d_in[14];
  const float* g_hbn   = (const float*)d_in[15];
  const float* be_hbn  = (const float*)d_in[16];
  const float* w_outm  = (const float*)d_in[17];
  const float* g_obn   = (const float*)d_in[18];
  const float* be_obn  = (const float*)d_in[19];
  const float* w_g     = (const float*)d_in[20];
  const float* b_g     = (const float*)d_in[21];
  const float* w_theta = (const float*)d_in[22];
  const float* b_theta = (const float*)d_in[23];
  const float* w_phi   = (const float*)d_in[24];
  const float* b_phi   = (const float*)d_in[25];
  const float* w_W     = (const float*)d_in[26];
  const float* b_W     = (const float*)d_in[27];
  const float* g_Wbn   = (const float*)d_in[28];
  const float* be_Wbn  = (const float*)d_in[29];
  const float* w5      = (const float*)d_in[30];
  const float* b5      = (const float*)d_in[31];
  const float* g_bn5   = (const float*)d_in[32];
  const float* be_bn5  = (const float*)d_in[33];
  const float* w6      = (const float*)d_in[34];
  const float* b6      = (const float*)d_in[35];
  const int*   idx_1   = (const int*)d_in[36];

  float* out0 = (float*)d_out;
  float* out1 = out0 + (size_t)BB * CO * NN;

  char* base = (char*)d_ws;
  size_t off = 0;
  auto alloc = [&](size_t bytes) -> char* {
    char* p = base + off;
    off += (bytes + 255) & ~(size_t)255;
    return p;
  };
  int*   inner  = (int*)  alloc((size_t)INNER * 4);
  int*   idx3   = (int*)  alloc((size_t)BB * NN * 3 * 4);
  float* w3     = (float*)alloc((size_t)BB * NN * 3 * 4);
  float* diff   = (float*)alloc((size_t)BB * NN * 4);
  int*   Hidx   = (int*)  alloc((size_t)BB * HH * 4);
  float* preds  = (float*)alloc((size_t)BB * NN * CLS * 4);
  float* HpA    = (float*)alloc((size_t)BB * HH * 149 * 4);
  float* Hp2    = (float*)alloc((size_t)BB * HH * CO * 4);
  float* xt     = (float*)alloc((size_t)BB * NN * CO * 4);
  char*  RI     =         alloc((size_t)BB * NN * 256 * 4);     // 32MB region
  char*  RX     =         alloc((size_t)BB * NN * 256 * 4);     // 32MB region
  float* p2t    = (float*)alloc((size_t)BB * SS * 256 * 4);
  if (off > ws_size) return;

  // region aliases (lifetimes disjoint):
  float* interp  = (float*)RI;                                  // steps 4-5
  u16*   thetab  = (u16*)RI;                                    // 13-14 (8MB)
  float* yattn   = (float*)(RI + (size_t)BB * NN * CO * 4);     // 14-15 (16MB)
  float* x2      = (float*)RX;                                  // 5-6   (32MB)
  u16*   phib    = (u16*)RX;                                    // 12-14 (2MB)
  u16*   gxT     = (u16*)(RX + (size_t)4 * 1024 * 1024);        // 11-14 (2MB)
  float* zbuf    = (float*)RX;                                  // 15-16 (16MB)
  float* npo     = (float*)(RX + (size_t)BB * NN * CO * 4);     // 16-18 (16MB)
  float* h5      = (float*)RX;                                  // 18-19
  float* logits  = preds;                                       // 19-20

  // 1. inner indices
  inner_idx_k<<<1, 512, 0, stream>>>(inner);

  // 2. transpose points2 (B,256,S) -> (B,S,256)
  transpose_k<<<dim3(SS/32, 256/32, BB), dim3(32, 8), 0, stream>>>(
      points2, p2t, 256, SS, (long long)256 * SS, (long long)SS * 256);

  // 3. 3-NN
  knn_k<<<dim3(NN/256, BB), 256, 0, stream>>>(xyz1, xyz2, idx3, w3);

  // 4. interpolate
  interp_k<<<dim3(NN, BB), 256, 0, stream>>>(p2t, lastpred, idx3, w3, interp, preds);

  // 5. mlp0 (z-batched over B)
  {
    GemmP p{};
    p.A = points1; p.A1T = 1; p.lda1 = NN; p.K1 = 256;
    p.A2 = interp;
    p.W = w_mlp0;
    p.bias = b_mlp0; p.bng = g_bn0; p.bnb = be_bn0;
    p.C = x2;
    p.M = NN; p.Nc = 256; p.K = 512; p.act = 1;
    p.zA = (long long)256 * NN; p.zA2 = (long long)NN * 256; p.zC = (long long)NN * 256;
    gemm_k<<<dim3(4, 128, BB), 256, 0, stream>>>(p);
  }

  // 6. mlp1 -> xt (f32; feeds diff/topk and residual exactly as before)
  {
    GemmP p{};
    p.A = x2; p.K1 = 256; p.W = w_mlp1;
    p.bias = b_mlp1; p.bng = g_bn1; p.bnb = be_bn1;
    p.C = xt; p.M = BB * NN; p.Nc = CO; p.K = 256; p.act = 1;
    gemm_k<<<ggrid(BB * NN, CO), 256, 0, stream>>>(p);
  }

  // 7. KNN feature variance score
  diff_k<<<BB * NN, 128, 0, stream>>>(xt, idx_1, diff);

  // 8. per-batch top-1638 (+ inner)
  topk_k<<<BB, 1024, 0, stream>>>(diff, inner, Hidx);

  // 9. gather Hp rows
  hpgather_k<<<dim3(HH, BB), 192, 0, stream>>>(xt, preds, Hidx, HpA);

  // 10. conv_h
  {
    GemmP p{};
    p.A = HpA; p.K1 = 149; p.W = w_h;
    p.bng = g_hbn; p.bnb = be_hbn;
    p.C = Hp2; p.M = BB * HH; p.Nc = CO; p.K = 149; p.act = 2;
    gemm_k<<<ggrid(BB * HH, CO), 256, 0, stream>>>(p);
  }
  // 11. g_x -> gxT (bf16, transposed per batch, ld 2048)
  {
    GemmP p{};
    p.A = Hp2; p.K1 = CO; p.W = w_g; p.bias = b_g;
    p.C = (float*)gxT; p.M = BB * HH; p.Nc = CO; p.K = CO; p.act = 0; p.omode = 2;
    gemm_k<<<ggrid(BB * HH, CO), 256, 0, stream>>>(p);
  }
  // 12. phi -> phib (bf16 row-major)
  {
    GemmP p{};
    p.A = Hp2; p.K1 = CO; p.W = w_phi; p.bias = b_phi;
    p.C = (float*)phib; p.M = BB * HH; p.Nc = CO; p.K = CO; p.act = 0; p.omode = 1;
    gemm_k<<<ggrid(BB * HH, CO), 256, 0, stream>>>(p);
  }
  // 13. theta -> thetab (bf16 row-major)
  {
    GemmP p{};
    p.A = xt; p.K1 = CO; p.W = w_theta; p.bias = b_theta;
    p.C = (float*)thetab; p.M = BB * NN; p.Nc = CO; p.K = CO; p.act = 0; p.omode = 1;
    gemm_k<<<ggrid(BB * NN, CO), 256, 0, stream>>>(p);
  }

  // 14. MFMA flash attention
  attn_mfma_k<<<dim3(NN/64, BB), 256, 0, stream>>>(thetab, phib, gxT, yattn);

  // 15. z = bn_W(W_W*y + b_W) + x
  {
    GemmP p{};
    p.A = yattn; p.K1 = CO; p.W = w_W; p.bias = b_W;
    p.bng = g_Wbn; p.bnb = be_Wbn; p.res = xt;
    p.C = zbuf; p.M = BB * NN; p.Nc = CO; p.K = CO; p.act = 0;
    gemm_k<<<ggrid(BB * NN, CO), 256, 0, stream>>>(p);
  }
  // 16. new_points_out
  {
    GemmP p{};
    p.A = zbuf; p.K1 = CO; p.W = w_outm;
    p.bng = g_obn; p.bnb = be_obn;
    p.C = npo; p.M = BB * NN; p.Nc = CO; p.K = CO; p.act = 2;
    gemm_k<<<ggrid(BB * NN, CO), 256, 0, stream>>>(p);
  }
  // 17. transpose npo -> out0
  transpose_k<<<dim3(CO/32, NN/32, BB), dim3(32, 8), 0, stream>>>(
      npo, out0, NN, CO, (long long)NN * CO, (long long)CO * NN);

  // 18. h5
  {
    GemmP p{};
    p.A = npo; p.K1 = CO; p.W = w5; p.bias = b5;
    p.bng = g_bn5; p.bnb = be_bn5;
    p.C = h5; p.M = BB * NN; p.Nc = 32; p.K = CO; p.act = 1;
    gemm_k<<<ggrid(BB * NN, 32), 256, 0, stream>>>(p);
  }
  // 19. logits
  {
    GemmP p{};
    p.A = h5; p.K1 = 32; p.W = w6; p.bias = b6;
    p.C = logits; p.M = BB * NN; p.Nc = CLS; p.K = 32; p.act = 0;
    gemm_k<<<ggrid(BB * NN, CLS), 256, 0, stream>>>(p);
  }
  // 20. log_softmax
  logsm_k<<<(BB * NN + 255) / 256, 256, 0, stream>>>(logits, out1);
}

// Round 4
// 923.071 us; speedup vs baseline: 7.3948x; 1.1681x over previous
//
#include <hip/hip_runtime.h>
#include <stdint.h>
#include <math.h>

// ---------------------------------------------------------------------------
// IAF_PointNetFeaturePropagation: bf16-MFMA GEMM chain + MFMA flash attention.
// B=4, N=8192, S=2048, K=20, D1=D2=256, CO=128, CLS=21, H=1638+409=2047
// ---------------------------------------------------------------------------

namespace {

constexpr int BB   = 4;
constexpr int NN   = 8192;
constexpr int SS   = 2048;
constexpr int KNB  = 20;
constexpr int CO   = 128;
constexpr int CLS  = 21;
constexpr int HH   = 2047;
constexpr int OUTER= 1638;
constexpr int INNER= 409;

typedef unsigned short u16;
typedef short bf8 __attribute__((ext_vector_type(8)));   // 8 bf16 in 4 VGPRs
typedef float f4  __attribute__((ext_vector_type(4)));   // MFMA accumulator

__device__ inline u16 f2bf(float f) {                    // round-nearest-even
  uint32_t x = __float_as_uint(f);
  return (u16)((x + 0x7FFFu + ((x >> 16) & 1u)) >> 16);
}

// ======================= numpy default_rng(0).choice(8192,409,replace=False)
__global__ __launch_bounds__(512) void inner_idx_k(int* __restrict__ out) {
  __shared__ uint64_t hs[512];
  hs[threadIdx.x] = ~0ull;
  __syncthreads();
  if (threadIdx.x != 0) return;

  uint32_t pool[4];
  uint32_t hc = 0x43b0d7e5u;
  auto hashmix = [&hc](uint32_t v) -> uint32_t {
    v ^= hc; hc *= 0x931e8875u; v *= hc; v ^= v >> 16; return v;
  };
  auto mixf = [](uint32_t x, uint32_t y) -> uint32_t {
    uint32_t r = x * 0xca01f9ddu; r ^= y * 0x4973f715u; r ^= r >> 16; return r;
  };
  pool[0] = hashmix(0u); pool[1] = hashmix(0u);
  pool[2] = hashmix(0u); pool[3] = hashmix(0u);
  for (int s = 0; s < 4; ++s)
    for (int d = 0; d < 4; ++d)
      if (s != d) pool[d] = mixf(pool[d], hashmix(pool[s]));

  uint32_t st32[8];
  uint32_t hb = 0x8b51f9ddu;
  for (int i = 0; i < 8; ++i) {
    uint32_t dv = pool[i & 3];
    dv ^= hb; hb *= 0x58f38dedu; dv *= hb; dv ^= dv >> 16;
    st32[i] = dv;
  }
  uint64_t s64[4];
  for (int i = 0; i < 4; ++i)
    s64[i] = (uint64_t)st32[2*i] | ((uint64_t)st32[2*i+1] << 32);

  typedef unsigned __int128 u128;
  const u128 MUL = ((u128)2549297995355413924ull << 64) | (u128)4865540595714422341ull;
  u128 inc   = (((((u128)s64[2]) << 64) | (u128)s64[3]) << 1) | 1;
  u128 state = inc;
  state += (((u128)s64[0]) << 64) | (u128)s64[1];
  state = state * MUL + inc;

  bool has32 = false; uint32_t buf32 = 0;
  auto next32 = [&]() -> uint32_t {
    if (has32) { has32 = false; return buf32; }
    state = state * MUL + inc;
    uint64_t hi = (uint64_t)(state >> 64), lo = (uint64_t)state;
    uint64_t x = hi ^ lo;
    unsigned rot = (unsigned)(state >> 122);
    uint64_t v = (x >> rot) | (x << ((64u - rot) & 63u));
    has32 = true; buf32 = (uint32_t)(v >> 32);
    return (uint32_t)v;
  };

  for (int j = NN - INNER; j < NN; ++j) {
    uint32_t rng = (uint32_t)j, rng_excl = rng + 1u;
    uint64_t m = (uint64_t)next32() * (uint64_t)rng_excl;
    uint32_t leftover = (uint32_t)m;
    if (leftover < rng_excl) {
      uint32_t threshold = (0xFFFFFFFFu - rng) % rng_excl;
      while (leftover < threshold) {
        m = (uint64_t)next32() * (uint64_t)rng_excl;
        leftover = (uint32_t)m;
      }
    }
    uint64_t val = m >> 32;
    uint32_t loc = (uint32_t)val & 511u;
    while (hs[loc] != ~0ull && hs[loc] != val) loc = (loc + 1u) & 511u;
    uint64_t chosen;
    if (hs[loc] == ~0ull) { hs[loc] = val; chosen = val; }
    else                  { hs[loc] = (uint64_t)j; chosen = (uint64_t)j; }
    out[j - (NN - INNER)] = (int)chosen;
  }
}

// ======================= generic 32x32-tiled f32 transpose (npo -> out0)
__global__ void transpose_k(const float* __restrict__ in, float* __restrict__ out,
                            int R, int Cc, long long inB, long long outB) {
  __shared__ float t[32][33];
  const float* ib = in  + (long long)blockIdx.z * inB;
  float*       ob = out + (long long)blockIdx.z * outB;
  int c0 = blockIdx.x * 32, r0 = blockIdx.y * 32;
  int tx = threadIdx.x, ty = threadIdx.y;
  for (int i = 0; i < 32; i += 8) {
    int r = r0 + ty + i, c = c0 + tx;
    if (r < R && c < Cc) t[ty + i][tx] = ib[(size_t)r * Cc + c];
  }
  __syncthreads();
  for (int i = 0; i < 32; i += 8) {
    int c = c0 + ty + i, r = r0 + tx;
    if (r < R && c < Cc) ob[(size_t)c * R + r] = t[tx][ty + i];
  }
}

// ======================= points2 transpose (B,256,S)->(B,S,256) f32 (for interp)
__global__ void transpose2_k(const float* __restrict__ in, float* __restrict__ out) {
  __shared__ float t[32][33];
  int b = blockIdx.z;
  int c0 = blockIdx.x * 32, r0 = blockIdx.y * 32;   // r over 256 rows, c over S
  const float* ib = in  + (size_t)b * 256 * SS;
  float*       ob = out + (size_t)b * SS * 256;
  int tx = threadIdx.x, ty = threadIdx.y;
  for (int i = 0; i < 32; i += 8)
    t[ty + i][tx] = ib[(size_t)(r0 + ty + i) * SS + c0 + tx];
  __syncthreads();
  for (int i = 0; i < 32; i += 8)
    ob[(size_t)(c0 + ty + i) * 256 + r0 + tx] = t[tx][ty + i];
}

// ======================= points1 (B,256,N) f32 -> A0 (B*N,512) bf16 cols 0..255
__global__ __launch_bounds__(256) void tcvt_k(const float* __restrict__ in,
                                              u16* __restrict__ A0) {
  __shared__ float t[64][33];
  const int b = blockIdx.z;
  const int n0 = blockIdx.x * 32, c0 = blockIdx.y * 64;
  {
    const int tn = threadIdx.x & 31, tc0 = threadIdx.x >> 5;
    #pragma unroll
    for (int i = 0; i < 8; ++i) {
      const int c = tc0 * 8 + i;
      t[c][tn] = in[((size_t)b * 256 + c0 + c) * NN + n0 + tn];
    }
  }
  __syncthreads();
  {
    const int cg = threadIdx.x & 7, n = threadIdx.x >> 3;
    u16 tmp[8];
    #pragma unroll
    for (int j = 0; j < 8; ++j) tmp[j] = f2bf(t[cg * 8 + j][n]);
    *(bf8*)&A0[((size_t)b * NN + n0 + n) * 512 + c0 + cg * 8] = *(bf8*)tmp;
  }
}

// ======================= weight f32 -> bf16 (K padded with zeros)
struct WcvP { const float* src; u16* dst; int rows; int K; int Kpad; };
struct WcvAll { WcvP e[8]; };
__global__ __launch_bounds__(512) void wcvt_k(WcvAll a) {
  WcvP p = a.e[blockIdx.y];
  int total = p.rows * p.Kpad;
  for (int i = blockIdx.x * 512 + threadIdx.x; i < total; i += gridDim.x * 512) {
    int r = i / p.Kpad, k = i - r * p.Kpad;
    p.dst[i] = (k < p.K) ? f2bf(p.src[(size_t)r * p.K + k]) : (u16)0;
  }
}

// ======================= 3-NN over S=2048
__global__ __launch_bounds__(256) void knn_k(const float* __restrict__ xyz1,
                                             const float* __restrict__ xyz2,
                                             int* __restrict__ idx3,
                                             float* __restrict__ w3) {
  __shared__ float X[SS], Y[SS], Z[SS], SSQ[SS];
  int b = blockIdx.y;
  const float* x2 = xyz2 + (size_t)b * SS * 3;
  for (int i = threadIdx.x; i < SS; i += 256) {
    float x = x2[i*3], y = x2[i*3+1], z = x2[i*3+2];
    X[i] = x; Y[i] = y; Z[i] = z; SSQ[i] = x*x + y*y + z*z;
  }
  __syncthreads();
  int n = blockIdx.x * 256 + threadIdx.x;
  const float* p = xyz1 + ((size_t)b * NN + n) * 3;
  float px = p[0], py = p[1], pz = p[2];
  float ss1 = px*px + py*py + pz*pz;
  float d0 = 3.4e38f, d1 = 3.4e38f, d2 = 3.4e38f;
  int   i0 = 0, i1 = 0, i2 = 0;
  for (int s = 0; s < SS; ++s) {
    float d = (ss1 + SSQ[s]) - 2.0f * (px*X[s] + py*Y[s] + pz*Z[s]);
    if (d < d2) {
      if (d < d1) {
        d2 = d1; i2 = i1;
        if (d < d0) { d1 = d0; i1 = i0; d0 = d; i0 = s; }
        else        { d1 = d;  i1 = s; }
      } else { d2 = d; i2 = s; }
    }
  }
  d0 = fmaxf(d0, 1e-10f); d1 = fmaxf(d1, 1e-10f); d2 = fmaxf(d2, 1e-10f);
  float w0 = 1.f/d0, w1 = 1.f/d1, w2 = 1.f/d2;
  float ws = w0 + w1 + w2;
  size_t o = (size_t)b * NN + n;
  idx3[o*3] = i0; idx3[o*3+1] = i1; idx3[o*3+2] = i2;
  w3[o*3] = w0/ws; w3[o*3+1] = w1/ws; w3[o*3+2] = w2/ws;
}

// ======================= interpolation gather -> A0 cols 256..511 (bf16) + preds f32
__global__ __launch_bounds__(256) void interp_k(const float* __restrict__ p2t,
                                                const float* __restrict__ lastpred,
                                                const int* __restrict__ idx3,
                                                const float* __restrict__ w3,
                                                u16* __restrict__ A0,
                                                float* __restrict__ preds) {
  int b = blockIdx.y, n = blockIdx.x;
  size_t o = (size_t)b * NN + n;
  int i0 = idx3[o*3], i1 = idx3[o*3+1], i2 = idx3[o*3+2];
  float w0 = w3[o*3], w1 = w3[o*3+1], w2 = w3[o*3+2];
  const float* pb = p2t + (size_t)b * SS * 256;
  int c = threadIdx.x;
  float v = w0 * pb[(size_t)i0*256 + c]
          + w1 * pb[(size_t)i1*256 + c]
          + w2 * pb[(size_t)i2*256 + c];
  A0[o*512 + 256 + c] = f2bf(v);
  if (c < CLS) {
    const float* lp = lastpred + (size_t)b * SS * CLS;
    preds[o*CLS + c] = w0 * lp[i0*CLS + c] + w1 * lp[i1*CLS + c] + w2 * lp[i2*CLS + c];
  }
}

// ======================= bf16 MFMA GEMM, 128x128 tile, fused epilogue
// A (M,K) bf16 rm; W (Nc,K) bf16 rm; K multiple of 64.
// omode: 0 f32 rm, 1 bf16 rm, 2 bf16 transposed (B,Nc,2048) per HH-batch.
struct MgP {
  const u16* A; const u16* W;
  const float* bias; const float* bng; const float* bnb; const float* res;
  void* C; float* C2;
  int M, Nc, K, act, omode;
};

__global__ __launch_bounds__(256) void mgemm_k(MgP p) {
  __shared__ u16 As[128 * 64];
  __shared__ u16 Ws[128 * 64];
  const int tid = threadIdx.x;
  const int wave = tid >> 6, lane = tid & 63;
  const int l15 = lane & 15, l4 = lane >> 4;
  const int wr = wave >> 1, wc = wave & 1;
  const int bm = blockIdx.y * 128, bn = blockIdx.x * 128;

  f4 acc[4][4];
  #pragma unroll
  for (int i = 0; i < 4; ++i)
    #pragma unroll
    for (int j = 0; j < 4; ++j) acc[i][j] = (f4){0.f, 0.f, 0.f, 0.f};

  for (int k0 = 0; k0 < p.K; k0 += 64) {
    __syncthreads();
    #pragma unroll
    for (int it = 0; it < 4; ++it) {
      int id = it * 256 + tid;
      int r = id >> 3, ch = id & 7;
      int gm = bm + r;
      bf8 va = {0,0,0,0,0,0,0,0};
      if (gm < p.M) va = *(const bf8*)(p.A + (size_t)gm * p.K + k0 + ch * 8);
      *(bf8*)&As[r * 64 + ((ch ^ (r & 7)) << 3)] = va;
      int gn = bn + r;
      bf8 vb = {0,0,0,0,0,0,0,0};
      if (gn < p.Nc) vb = *(const bf8*)(p.W + (size_t)gn * p.K + k0 + ch * 8);
      *(bf8*)&Ws[r * 64 + ((ch ^ (r & 7)) << 3)] = vb;
    }
    __syncthreads();
    #pragma unroll
    for (int ks = 0; ks < 2; ++ks) {
      bf8 af[4], bf[4];
      #pragma unroll
      for (int mf = 0; mf < 4; ++mf) {
        int m = wr * 64 + mf * 16 + l15;
        af[mf] = *(const bf8*)&As[m * 64 + (((ks * 4 + l4) ^ (m & 7)) << 3)];
      }
      #pragma unroll
      for (int nf = 0; nf < 4; ++nf) {
        int n = wc * 64 + nf * 16 + l15;
        bf[nf] = *(const bf8*)&Ws[n * 64 + (((ks * 4 + l4) ^ (n & 7)) << 3)];
      }
      #pragma unroll
      for (int mf = 0; mf < 4; ++mf)
        #pragma unroll
        for (int nf = 0; nf < 4; ++nf)
          acc[mf][nf] = __builtin_amdgcn_mfma_f32_16x16x32_bf16(af[mf], bf[nf], acc[mf][nf], 0, 0, 0);
    }
  }

  const float bnden = sqrtf(1.0f + 1e-5f);
  #pragma unroll
  for (int mf = 0; mf < 4; ++mf) {
    #pragma unroll
    for (int i = 0; i < 4; ++i) {
      const int r = bm + wr * 64 + mf * 16 + l4 * 4 + i;
      if (r >= p.M) continue;
      #pragma unroll
      for (int nf = 0; nf < 4; ++nf) {
        const int c = bn + wc * 64 + nf * 16 + l15;
        float v = acc[mf][nf][i];
        if (p.bias) v += p.bias[c];
        if (p.bng)  v = v * (p.bng[c] / bnden) + p.bnb[c];
        if (p.res)  v += p.res[(size_t)r * p.Nc + c];
        if (p.act == 1)      v = fmaxf(v, 0.f);
        else if (p.act == 2) v = (v >= 0.f) ? v : 0.2f * v;
        if (p.omode == 0) {
          ((float*)p.C)[(size_t)r * p.Nc + c] = v;
        } else if (p.omode == 1) {
          ((u16*)p.C)[(size_t)r * p.Nc + c] = f2bf(v);
        } else {
          const int bb = r / HH, rr = r - bb * HH;
          ((u16*)p.C)[((size_t)(bb * p.Nc + c)) * 2048 + rr] = f2bf(v);
        }
        if (p.C2) p.C2[(size_t)r * p.Nc + c] = v;
      }
    }
  }
}

// ======================= generic f32 GEMM (small tail layers only)
struct GemmP {
  const float* A;  const float* W;
  const float* bias; const float* bng; const float* bnb;
  float* C;
  int M, Nc, K, act;
};

__global__ __launch_bounds__(256) void gemm_k(GemmP p) {
  __shared__ float As[16][68];
  __shared__ float Ws[16][68];
  const int bm = blockIdx.y * 64, bn = blockIdx.x * 64;
  const int tid = threadIdx.x;
  const int tx = tid & 15, ty = tid >> 4;
  float acc[4][4] = {{0.f,0.f,0.f,0.f},{0.f,0.f,0.f,0.f},{0.f,0.f,0.f,0.f},{0.f,0.f,0.f,0.f}};
  for (int k0 = 0; k0 < p.K; k0 += 16) {
    {
      const int kk = tid & 15, mb = tid >> 4;
      #pragma unroll
      for (int mm = mb; mm < 64; mm += 16) {
        const int gm = bm + mm, gk = k0 + kk;
        As[kk][mm] = (gm < p.M && gk < p.K) ? p.A[(size_t)gm * p.K + gk] : 0.f;
      }
    }
    {
      const int kk = tid & 15, nb = tid >> 4;
      #pragma unroll
      for (int nn = nb; nn < 64; nn += 16) {
        const int gn = bn + nn, gk = k0 + kk;
        Ws[kk][nn] = (gn < p.Nc && gk < p.K) ? p.W[(size_t)gn * p.K + gk] : 0.f;
      }
    }
    __syncthreads();
    #pragma unroll
    for (int kk = 0; kk < 16; ++kk) {
      const float4 av = *(const float4*)&As[kk][ty * 4];
      const float4 bv = *(const float4*)&Ws[kk][tx * 4];
      acc[0][0] += av.x*bv.x; acc[0][1] += av.x*bv.y; acc[0][2] += av.x*bv.z; acc[0][3] += av.x*bv.w;
      acc[1][0] += av.y*bv.x; acc[1][1] += av.y*bv.y; acc[1][2] += av.y*bv.z; acc[1][3] += av.y*bv.w;
      acc[2][0] += av.z*bv.x; acc[2][1] += av.z*bv.y; acc[2][2] += av.z*bv.z; acc[2][3] += av.z*bv.w;
      acc[3][0] += av.w*bv.x; acc[3][1] += av.w*bv.y; acc[3][2] += av.w*bv.z; acc[3][3] += av.w*bv.w;
    }
    __syncthreads();
  }
  const float bnden = sqrtf(1.0f + 1e-5f);
  #pragma unroll
  for (int i = 0; i < 4; ++i) {
    const int r = bm + ty * 4 + i;
    if (r >= p.M) break;
    #pragma unroll
    for (int j = 0; j < 4; ++j) {
      const int c = bn + tx * 4 + j;
      if (c >= p.Nc) continue;
      float v = acc[i][j];
      if (p.bias) v += p.bias[c];
      if (p.bng)  v = v * (p.bng[c] / bnden) + p.bnb[c];
      if (p.act == 1)      v = fmaxf(v, 0.f);
      else if (p.act == 2) v = (v >= 0.f) ? v : 0.2f * v;
      p.C[(size_t)r * p.Nc + c] = v;
    }
  }
}

// ======================= bf16-MFMA flash attention over the 2047-pool
__global__ __launch_bounds__(256) void attn_mfma_k(
    const u16* __restrict__ thetab,   // (B*N,128) bf16 rm
    const u16* __restrict__ phib,     // (B*H,128) bf16 rm
    const u16* __restrict__ gxT,      // (B,128,2048) bf16 (col 2047 junk)
    u16* __restrict__ y)              // (B*N,128) bf16
{
  __shared__ u16 Kt[64 * 128];
  __shared__ u16 Vt[128 * 64];
  __shared__ u16 Pt[64 * 72];
  const int b    = blockIdx.y;
  const int row0 = blockIdx.x * 64;
  const int tid  = threadIdx.x;
  const int wave = tid >> 6;
  const int lane = tid & 63;
  const int l15  = lane & 15, l4 = lane >> 4;

  bf8 aq[4];
  {
    const u16* tq = thetab + ((size_t)(b * NN + row0 + wave * 16 + l15)) * 128;
    #pragma unroll
    for (int ks = 0; ks < 4; ++ks)
      aq[ks] = *(const bf8*)(tq + ks * 32 + l4 * 8);
  }

  f4 acc[8];
  #pragma unroll
  for (int i = 0; i < 8; ++i) acc[i] = (f4){0.f, 0.f, 0.f, 0.f};
  float mrow[4] = {-3e38f, -3e38f, -3e38f, -3e38f};
  float lrow[4] = {0.f, 0.f, 0.f, 0.f};

  const u16* phbase = phib + (size_t)b * HH * 128;
  const u16* gxbase = gxT  + (size_t)b * 128 * 2048;

  for (int h0 = 0; h0 < 2048; h0 += 64) {
    __syncthreads();
    #pragma unroll
    for (int it = 0; it < 4; ++it) {
      int id = it * 256 + tid;
      int r = id >> 4, ch = id & 15;
      int gp = h0 + r;
      bf8 vv = {0,0,0,0,0,0,0,0};
      if (gp < HH) vv = *(const bf8*)(phbase + (size_t)gp * 128 + ch * 8);
      *(bf8*)&Kt[r * 128 + ((ch ^ (r & 7)) << 3)] = vv;
    }
    #pragma unroll
    for (int it = 0; it < 4; ++it) {
      int id = it * 256 + tid;
      int c = id >> 3, ch = id & 7;
      bf8 vv = *(const bf8*)(gxbase + (size_t)c * 2048 + h0 + ch * 8);
      *(bf8*)&Vt[c * 64 + ((ch ^ (c & 7)) << 3)] = vv;
    }
    __syncthreads();

    f4 sacc[4];
    #pragma unroll
    for (int t = 0; t < 4; ++t) sacc[t] = (f4){0.f, 0.f, 0.f, 0.f};
    #pragma unroll
    for (int ks = 0; ks < 4; ++ks) {
      #pragma unroll
      for (int t = 0; t < 4; ++t) {
        const int pr = t * 16 + l15;
        const int ch = (ks * 4 + l4) ^ (pr & 7);
        bf8 bk = *(const bf8*)&Kt[pr * 128 + ch * 8];
        sacc[t] = __builtin_amdgcn_mfma_f32_16x16x32_bf16(aq[ks], bk, sacc[t], 0, 0, 0);
      }
    }
    if (h0 + 64 > HH) {
      #pragma unroll
      for (int t = 0; t < 4; ++t)
        if (h0 + t * 16 + l15 >= HH)
          sacc[t] = (f4){-3e38f, -3e38f, -3e38f, -3e38f};
    }

    float e[4][4];
    #pragma unroll
    for (int r = 0; r < 4; ++r) {
      float tm = fmaxf(fmaxf(sacc[0][r], sacc[1][r]), fmaxf(sacc[2][r], sacc[3][r]));
      tm = fmaxf(tm, __shfl_xor(tm, 1));
      tm = fmaxf(tm, __shfl_xor(tm, 2));
      tm = fmaxf(tm, __shfl_xor(tm, 4));
      tm = fmaxf(tm, __shfl_xor(tm, 8));
      const float mn = fmaxf(mrow[r], tm);
      const float sc = __expf(mrow[r] - mn);
      mrow[r] = mn;
      float ps = 0.f;
      #pragma unroll
      for (int t = 0; t < 4; ++t) {
        float ev = __expf(sacc[t][r] - mn);
        e[t][r] = ev; ps += ev;
      }
      ps += __shfl_xor(ps, 1); ps += __shfl_xor(ps, 2);
      ps += __shfl_xor(ps, 4); ps += __shfl_xor(ps, 8);
      lrow[r] = lrow[r] * sc + ps;
      #pragma unroll
      for (int ct = 0; ct < 8; ++ct) acc[ct][r] *= sc;
    }
    #pragma unroll
    for (int r = 0; r < 4; ++r) {
      const int prow = wave * 16 + l4 * 4 + r;
      #pragma unroll
      for (int t = 0; t < 4; ++t)
        Pt[prow * 72 + t * 16 + l15] = f2bf(e[t][r]);
    }

    #pragma unroll
    for (int ks = 0; ks < 2; ++ks) {
      bf8 pa = *(const bf8*)&Pt[(wave * 16 + l15) * 72 + (ks * 4 + l4) * 8];
      #pragma unroll
      for (int ct = 0; ct < 8; ++ct) {
        const int c  = ct * 16 + l15;
        const int ch = (ks * 4 + l4) ^ (c & 7);
        bf8 bv = *(const bf8*)&Vt[c * 64 + ch * 8];
        acc[ct] = __builtin_amdgcn_mfma_f32_16x16x32_bf16(pa, bv, acc[ct], 0, 0, 0);
      }
    }
  }

  u16* yo = y + ((size_t)(b * NN + row0 + wave * 16 + l4 * 4)) * 128;
  #pragma unroll
  for (int r = 0; r < 4; ++r) {
    const float inv = 1.0f / lrow[r];
    #pragma unroll
    for (int ct = 0; ct < 8; ++ct)
      yo[(size_t)r * 128 + ct * 16 + l15] = f2bf(acc[ct][r] * inv);
  }
}

// ======================= diff[b,n] = sum_k sum_c (flat[idx1]-xt)^2
__global__ __launch_bounds__(128) void diff_k(const float* __restrict__ xt,
                                              const int* __restrict__ idx1,
                                              float* __restrict__ diff) {
  __shared__ float r2[2];
  int bn = blockIdx.x;
  int c  = threadIdx.x;
  float xc = xt[(size_t)bn * CO + c];
  const int* id = idx1 + (size_t)bn * KNB;
  float acc = 0.f;
  #pragma unroll
  for (int k = 0; k < KNB; ++k) {
    int ix = id[k];
    float d = xt[(size_t)ix * CO + c] - xc;
    acc += d * d;
  }
  for (int o = 32; o; o >>= 1) acc += __shfl_xor(acc, o);
  if ((c & 63) == 0) r2[c >> 6] = acc;
  __syncthreads();
  if (c == 0) diff[bn] = r2[0] + r2[1];
}

// ======================= per-batch top-1638 bitonic + append inner
__global__ __launch_bounds__(1024) void topk_k(const float* __restrict__ diff,
                                               const int* __restrict__ inner,
                                               int* __restrict__ Hidx) {
  __shared__ uint64_t kv[NN];
  int b = blockIdx.x, tid = threadIdx.x;
  for (int i = tid; i < NN; i += 1024) {
    uint32_t bits = __float_as_uint(diff[(size_t)b * NN + i]);
    kv[i] = ((uint64_t)bits << 32) | (uint64_t)(NN - 1 - i);
  }
  __syncthreads();
  for (int k = 2; k <= NN; k <<= 1) {
    for (int j = k >> 1; j > 0; j >>= 1) {
      for (int t = tid; t < NN/2; t += 1024) {
        int i = ((t & ~(j - 1)) << 1) | (t & (j - 1));
        int q = i | j;
        uint64_t a = kv[i], c = kv[q];
        bool desc = ((i & k) == 0);
        bool sw = desc ? (a < c) : (a > c);
        if (sw) { kv[i] = c; kv[q] = a; }
      }
      __syncthreads();
    }
  }
  for (int t = tid; t < OUTER; t += 1024)
    Hidx[b * HH + t] = NN - 1 - (int)(kv[t] & 0xFFFFFFFFull);
  if (tid < INNER) Hidx[b * HH + OUTER + tid] = inner[tid];
}

// ======================= gather Hp rows -> bf16, K padded to 192
__global__ void hpgather_k(const float* __restrict__ xt,
                           const float* __restrict__ preds,
                           const int* __restrict__ Hidx,
                           u16* __restrict__ HpA) {
  int b = blockIdx.y, h = blockIdx.x;
  int src = Hidx[b * HH + h];
  size_t srow = (size_t)b * NN + src;
  size_t drow = (size_t)b * HH + h;
  int t = threadIdx.x;   // 192
  float v = 0.f;
  if (t < CO)            v = xt[srow * CO + t];
  else if (t < CO + CLS) v = preds[srow * CLS + (t - CO)];
  HpA[drow * 192 + t] = f2bf(v);
}

// ======================= log_softmax over 21 logits
__global__ __launch_bounds__(256) void logsm_k(const float* __restrict__ logits,
                                               float* __restrict__ out) {
  int r = blockIdx.x * 256 + threadIdx.x;
  if (r >= BB * NN) return;
  const float* l = logits + (size_t)r * CLS;
  float*       o = out    + (size_t)r * CLS;
  float m = l[0];
  #pragma unroll
  for (int i = 1; i < CLS; ++i) m = fmaxf(m, l[i]);
  float s = 0.f;
  #pragma unroll
  for (int i = 0; i < CLS; ++i) s += expf(l[i] - m);
  float lse = m + logf(s);
  #pragma unroll
  for (int i = 0; i < CLS; ++i) o[i] = l[i] - lse;
}

} // anonymous namespace

// ===========================================================================
extern "C" void kernel_launch(void* const* d_in, const int* in_sizes, int n_in,
                              void* d_out, int out_size, void* d_ws, size_t ws_size,
                              hipStream_t stream) {
  const float* xyz1    = (const float*)d_in[0];
  const float* xyz2    = (const float*)d_in[1];
  const float* points1 = (const float*)d_in[2];
  const float* points2 = (const float*)d_in[3];
  const float* lastpred= (const float*)d_in[5];
  const float* w_mlp0  = (const float*)d_in[6];
  const float* b_mlp0  = (const float*)d_in[7];
  const float* g_bn0   = (const float*)d_in[8];
  const float* be_bn0  = (const float*)d_in[9];
  const float* w_mlp1  = (const float*)d_in[10];
  const float* b_mlp1  = (const float*)d_in[11];
  const float* g_bn1   = (const float*)d_in[12];
  const float* be_bn1  = (const float*)d_in[13];
  const float* w_h     = (const float*)d_in[14];
  const float* g_hbn   = (const float*)d_in[15];
  const float* be_hbn  = (const float*)d_in[16];
  const float* w_outm  = (const float*)d_in[17];
  const float* g_obn   = (const float*)d_in[18];
  const float* be_obn  = (const float*)d_in[19];
  const float* w_g     = (const float*)d_in[20];
  const float* b_g     = (const float*)d_in[21];
  const float* w_theta = (const float*)d_in[22];
  const float* b_theta = (const float*)d_in[23];
  const float* w_phi   = (const float*)d_in[24];
  const float* b_phi   = (const float*)d_in[25];
  const float* w_W     = (const float*)d_in[26];
  const float* b_W     = (const float*)d_in[27];
  const float* g_Wbn   = (const float*)d_in[28];
  const float* be_Wbn  = (const float*)d_in[29];
  const float* w5      = (const float*)d_in[30];
  const float* b5      = (const float*)d_in[31];
  const float* g_bn5   = (const float*)d_in[32];
  const float* be_bn5  = (const float*)d_in[33];
  const float* w6      = (const float*)d_in[34];
  const float* b6      = (const float*)d_in[35];
  const int*   idx_1   = (const int*)d_in[36];

  float* out0 = (float*)d_out;
  float* out1 = out0 + (size_t)BB * CO * NN;

  char* base = (char*)d_ws;
  size_t off = 0;
  auto alloc = [&](size_t bytes) -> char* {
    char* p = base + off;
    off += (bytes + 255) & ~(size_t)255;
    return p;
  };
  int*   inner  = (int*)  alloc((size_t)INNER * 4);
  int*   idx3   = (int*)  alloc((size_t)BB * NN * 3 * 4);
  float* w3     = (float*)alloc((size_t)BB * NN * 3 * 4);
  float* diff   = (float*)alloc((size_t)BB * NN * 4);
  int*   Hidx   = (int*)  alloc((size_t)BB * HH * 4);
  float* preds  = (float*)alloc((size_t)BB * NN * CLS * 4);
  u16*   HpA    = (u16*)  alloc((size_t)BB * HH * 192 * 2);
  u16*   Hp2b   = (u16*)  alloc((size_t)BB * HH * CO * 2);
  float* xt     = (float*)alloc((size_t)BB * NN * CO * 4);
  u16*   xtb    = (u16*)  alloc((size_t)BB * NN * CO * 2);      // later: zb
  u16*   phib   = (u16*)  alloc((size_t)BB * HH * CO * 2);
  u16*   gxT    = (u16*)  alloc((size_t)BB * CO * 2048 * 2);
  u16*   wbuf   = (u16*)  alloc((size_t)270336 * 2);
  char*  R1     =         alloc((size_t)BB * NN * 512 * 2);     // 33.5MB
  char*  R2     =         alloc((size_t)BB * NN * 256 * 2);     // 16MB
  if (off > ws_size) return;   // insufficient scratch (diagnostic)

  // weight bf16 buffers inside wbuf
  u16* w0b = wbuf;                 // 256x512
  u16* w1b = w0b + 256 * 512;      // 128x256
  u16* whb = w1b + 128 * 256;      // 128x192 (149 padded)
  u16* wgb = whb + 128 * 192;      // 128x128
  u16* wtb = wgb + 128 * 128;
  u16* wpb = wtb + 128 * 128;
  u16* wWb = wpb + 128 * 128;
  u16* wob = wWb + 128 * 128;

  // region aliases (lifetimes disjoint)
  u16*   A0     = (u16*)R1;                                     // steps 2-5
  u16*   thetab = (u16*)R1;                                     // 13-14 (8MB)
  u16*   yb     = (u16*)(R1 + (size_t)8 * 1024 * 1024);         // 14-15 (8MB)
  float* h5     = (float*)(R1 + (size_t)16 * 1024 * 1024);      // 18-19 (4MB)
  float* p2t    = (float*)R2;                                   // 2-4 (8MB)
  u16*   x2b    = (u16*)R2;                                     // 5-6 (16MB)
  float* npo    = (float*)R2;                                   // 16-18 (16MB)
  u16*   zb     = xtb;                                          // 15-16 (xtb dead after 13)
  float* logits = preds;                                        // 19-20

  // 0. weight conversion (bf16, padded)
  {
    WcvAll wa;
    wa.e[0] = {w_mlp0, w0b, 256, 512, 512};
    wa.e[1] = {w_mlp1, w1b, 128, 256, 256};
    wa.e[2] = {w_h,    whb, 128, 149, 192};
    wa.e[3] = {w_g,    wgb, 128, 128, 128};
    wa.e[4] = {w_theta,wtb, 128, 128, 128};
    wa.e[5] = {w_phi,  wpb, 128, 128, 128};
    wa.e[6] = {w_W,    wWb, 128, 128, 128};
    wa.e[7] = {w_outm, wob, 128, 128, 128};
    wcvt_k<<<dim3(32, 8), 512, 0, stream>>>(wa);
  }

  // 1. inner indices
  inner_idx_k<<<1, 512, 0, stream>>>(inner);

  // 2. transpose points2 -> p2t;  points1 -> A0 cols 0..255 (bf16)
  transpose2_k<<<dim3(SS/32, 256/32, BB), dim3(32, 8), 0, stream>>>(points2, p2t);
  tcvt_k<<<dim3(NN/32, 4, BB), 256, 0, stream>>>(points1, A0);

  // 3. 3-NN
  knn_k<<<dim3(NN/256, BB), 256, 0, stream>>>(xyz1, xyz2, idx3, w3);

  // 4. interpolate -> A0 cols 256..511 (bf16) + preds f32
  interp_k<<<dim3(NN, BB), 256, 0, stream>>>(p2t, lastpred, idx3, w3, A0, preds);

  // 5. mlp0: relu(bn0(W0·A0 + b0)) -> x2b bf16
  {
    MgP p{};
    p.A = A0; p.W = w0b; p.bias = b_mlp0; p.bng = g_bn0; p.bnb = be_bn0;
    p.C = x2b; p.M = BB * NN; p.Nc = 256; p.K = 512; p.act = 1; p.omode = 1;
    mgemm_k<<<dim3(2, 256), 256, 0, stream>>>(p);
  }
  // 6. mlp1 -> xtb bf16 + xt f32
  {
    MgP p{};
    p.A = x2b; p.W = w1b; p.bias = b_mlp1; p.bng = g_bn1; p.bnb = be_bn1;
    p.C = xtb; p.C2 = xt; p.M = BB * NN; p.Nc = CO; p.K = 256; p.act = 1; p.omode = 1;
    mgemm_k<<<dim3(1, 256), 256, 0, stream>>>(p);
  }

  // 7. KNN feature variance score
  diff_k<<<BB * NN, 128, 0, stream>>>(xt, idx_1, diff);

  // 8. per-batch top-1638 (+ inner)
  topk_k<<<BB, 1024, 0, stream>>>(diff, inner, Hidx);

  // 9. gather Hp rows (bf16, K=192 padded)
  hpgather_k<<<dim3(HH, BB), 192, 0, stream>>>(xt, preds, Hidx, HpA);

  // 10. conv_h: leaky(bn_h(W_h·Hp)) -> Hp2b bf16
  {
    MgP p{};
    p.A = HpA; p.W = whb; p.bng = g_hbn; p.bnb = be_hbn;
    p.C = Hp2b; p.M = BB * HH; p.Nc = CO; p.K = 192; p.act = 2; p.omode = 1;
    mgemm_k<<<dim3(1, 64), 256, 0, stream>>>(p);
  }
  // 11. g_x -> gxT (bf16 transposed per batch, ld 2048)
  {
    MgP p{};
    p.A = Hp2b; p.W = wgb; p.bias = b_g;
    p.C = gxT; p.M = BB * HH; p.Nc = CO; p.K = CO; p.act = 0; p.omode = 2;
    mgemm_k<<<dim3(1, 64), 256, 0, stream>>>(p);
  }
  // 12. phi -> phib bf16 rm
  {
    MgP p{};
    p.A = Hp2b; p.W = wpb; p.bias = b_phi;
    p.C = phib; p.M = BB * HH; p.Nc = CO; p.K = CO; p.act = 0; p.omode = 1;
    mgemm_k<<<dim3(1, 64), 256, 0, stream>>>(p);
  }
  // 13. theta -> thetab bf16 rm
  {
    MgP p{};
    p.A = xtb; p.W = wtb; p.bias = b_theta;
    p.C = thetab; p.M = BB * NN; p.Nc = CO; p.K = CO; p.act = 0; p.omode = 1;
    mgemm_k<<<dim3(1, 256), 256, 0, stream>>>(p);
  }

  // 14. MFMA flash attention -> yb bf16
  attn_mfma_k<<<dim3(NN/64, BB), 256, 0, stream>>>(thetab, phib, gxT, yb);

  // 15. z = bn_W(W_W·y + b_W) + xt -> zb bf16
  {
    MgP p{};
    p.A = yb; p.W = wWb; p.bias = b_W; p.bng = g_Wbn; p.bnb = be_Wbn; p.res = xt;
    p.C = zb; p.M = BB * NN; p.Nc = CO; p.K = CO; p.act = 0; p.omode = 1;
    mgemm_k<<<dim3(1, 256), 256, 0, stream>>>(p);
  }
  // 16. new_points_out = leaky(bn_o(W_outm·z)) -> npo f32
  {
    MgP p{};
    p.A = zb; p.W = wob; p.bng = g_obn; p.bnb = be_obn;
    p.C = npo; p.M = BB * NN; p.Nc = CO; p.K = CO; p.act = 2; p.omode = 0;
    mgemm_k<<<dim3(1, 256), 256, 0, stream>>>(p);
  }
  // 17. transpose npo -> out0
  transpose_k<<<dim3(CO/32, NN/32, BB), dim3(32, 8), 0, stream>>>(
      npo, out0, NN, CO, (long long)NN * CO, (long long)CO * NN);

  // 18. h5 = relu(bn5(W5·npo + b5))  (f32 tail)
  {
    GemmP p{};
    p.A = npo; p.W = w5; p.bias = b5; p.bng = g_bn5; p.bnb = be_bn5;
    p.C = h5; p.M = BB * NN; p.Nc = 32; p.K = CO; p.act = 1;
    gemm_k<<<dim3(1, 512), 256, 0, stream>>>(p);
  }
  // 19. logits = W6·h5 + b6
  {
    GemmP p{};
    p.A = h5; p.W = w6; p.bias = b6;
    p.C = logits; p.M = BB * NN; p.Nc = CLS; p.K = 32; p.act = 0;
    gemm_k<<<dim3(1, 512), 256, 0, stream>>>(p);
  }
  // 20. log_softmax
  logsm_k<<<(BB * NN + 255) / 256, 256, 0, stream>>>(logits, out1);
}